// Round 10
// baseline (262.822 us; speedup 1.0000x reference)
//
#include <hip/hip_runtime.h>
#include <hip/hip_bf16.h>
#include <math.h>

// Problem constants
#define DIM     192
#define HEADS   6
#define HEAD_DIM 32
#define NTOK    64          // tokens per window
#define IN_CC   16
#define TTOT    32768       // 8 * 64 * 64 tokens
#define NWIN    512

using bf16x8 = __attribute__((ext_vector_type(8))) short;
using f32x4  = __attribute__((ext_vector_type(4))) float;
typedef unsigned short ushort_t;

// fp32 -> bf16 round-to-nearest-even (finite inputs)
__device__ __forceinline__ ushort_t f2b(float f) {
    unsigned u = __float_as_uint(f);
    u += 0x7fffu + ((u >> 16) & 1u);
    return (ushort_t)(u >> 16);
}
__device__ __forceinline__ unsigned pk2(float a, float b) {
    return (unsigned)f2b(a) | ((unsigned)f2b(b) << 16);
}

// ---------------------------------------------------------------------------
// Merged weight fp32 -> bf16 conversion INTO MFMA FRAGMENT ORDER.
// W (NxK row-major) -> W' where element (o,k) lives at
//   frag = (o/16)*(K/8) + (k/8);  W'[frag*128 + (o%16)*8 + (k%8)]
__global__ __launch_bounds__(256) void cvt_all_kernel(
    const float* __restrict__ s0, const float* __restrict__ s1,
    const float* __restrict__ s2, const float* __restrict__ s3,
    ushort_t* __restrict__ d0, ushort_t* __restrict__ d1,
    ushort_t* __restrict__ d2, ushort_t* __restrict__ d3)
{
    const int bid = blockIdx.x;
    const float* src; ushort_t* dst; int off, K;
    if (bid < 108)      { src = s0; dst = d0; off = bid;       K = 192; }
    else if (bid < 144) { src = s1; dst = d1; off = bid - 108; K = 192; }
    else if (bid < 288) { src = s2; dst = d2; off = bid - 144; K = 192; }
    else                { src = s3; dst = d3; off = bid - 288; K = 768; }
    const int K8 = K >> 3;
    const int d  = (off * 256 + threadIdx.x) * 4;
    const int frag = d >> 7, win = d & 127;
    const int m16w = win >> 3, k7 = win & 7;
    const int oblk = frag / K8, kblk = frag - oblk * K8;
    const int o = oblk * 16 + m16w, k = kblk * 8 + k7;
    float4 v = *(const float4*)(src + (size_t)o * K + k);
    ushort4 ov;
    ov.x = f2b(v.x); ov.y = f2b(v.y); ov.z = f2b(v.z); ov.w = f2b(v.w);
    *(ushort4*)(dst + d) = ov;
}

// ---------------------------------------------------------------------------
// Kernel 1: LayerNorm1 fused with (B,C,H,W) -> (T,C) transpose.
__global__ __launch_bounds__(256) void ln1_kernel(
    const float* __restrict__ x, const float* __restrict__ g,
    const float* __restrict__ bb, float* __restrict__ outp,
    ushort_t* __restrict__ outh)
{
    __shared__ float xs[64][193];
    __shared__ float mu_s[64], rs_s[64];
    __shared__ float gs[192], bs[192];
    const int tid = threadIdx.x;
    const int t0  = blockIdx.x * 64;
    const int b   = t0 >> 12;
    const int hw0 = t0 & 4095;
    if (tid < 192) { gs[tid] = g[tid]; bs[tid] = bb[tid]; }
    const int tok = tid & 63, qq = tid >> 6;
    const float* xb = x + (size_t)b * (DIM * 4096) + hw0 + tok;
    #pragma unroll
    for (int it = 0; it < 48; ++it) {
        int c = it * 4 + qq;
        xs[tok][c] = xb[(size_t)c * 4096];
    }
    __syncthreads();
    const int tok2 = tid >> 2, p = tid & 3;
    float sum = 0.f;
    #pragma unroll
    for (int c = 0; c < 48; ++c) sum += xs[tok2][p * 48 + c];
    sum += __shfl_xor(sum, 1);
    sum += __shfl_xor(sum, 2);
    const float m = sum * (1.0f / 192.0f);
    float ss = 0.f;
    #pragma unroll
    for (int c = 0; c < 48; ++c) { float d = xs[tok2][p * 48 + c] - m; ss += d * d; }
    ss += __shfl_xor(ss, 1);
    ss += __shfl_xor(ss, 2);
    if (p == 0) {
        mu_s[tok2] = m;
        rs_s[tok2] = 1.0f / sqrtf(ss * (1.0f / 192.0f) + 1e-5f);
    }
    __syncthreads();
    float* ob = outp + (size_t)t0 * DIM;
    ushort_t* obh = outh + (size_t)t0 * DIM;
    #pragma unroll
    for (int it = 0; it < 48; ++it) {
        int idx = it * 256 + tid;
        int tk = idx / 192, c = idx % 192;
        float v = (xs[tk][c] - mu_s[tk]) * rs_s[tk] * gs[c] + bs[c];
        ob[idx] = v;
        obh[idx] = f2b(v);
    }
}

// ---------------------------------------------------------------------------
// Direct-fragment MFMA GEMM, 4 independent waves per 256-thread block
// (wave w owns tokens t0=(blockIdx.x*4+w)*64; all waves share o0 => W-frag
// loads hit L1). Zero barriers: each wave's epilogue uses its own Ct slice.
// A-frags direct from row-major global; W-frags from the FRAGMENT-ORDER
// weight buffer (1024 B coalesced per instr).
// epi: 0=bias->f32, 1=bias+res->f32, 2=bias+gelu->bf16, 3=bias->bf16,
//      4=bias+res->f32 stored TRANSPOSED to (B,C,64,64) NCHW layout.
__global__ __launch_bounds__(256) void gemm_mfma(
    const ushort_t* __restrict__ A, const ushort_t* __restrict__ Wf,
    const float* __restrict__ bias, const float* __restrict__ res,
    float* __restrict__ outf, ushort_t* __restrict__ outh,
    int N, int K, int epi)
{
    __shared__ __align__(16) float Ct[4][32][68];   // 34.8 KB, per-wave slices
    const int tid  = threadIdx.x;
    const int wave = tid >> 6, lane = tid & 63;
    const int m16 = lane & 15, quad = lane >> 4;
    const int t0 = (blockIdx.x * 4 + wave) * 64, o0 = blockIdx.y * 64;
    const int K8 = K >> 3;
    float (*Cw)[68] = Ct[wave];

    f32x4 acc[4][4];   // acc[i][j]: tokens 16i+m16 (cols), outs 16j+quad*4+r (rows)
    #pragma unroll
    for (int i = 0; i < 4; ++i)
        #pragma unroll
        for (int j = 0; j < 4; ++j)
            acc[i][j] = (f32x4)(0.0f);

    const ushort_t* Ab = A + (size_t)t0 * K + quad * 8;
    const ushort_t* Wb = Wf + (size_t)(o0 >> 4) * K8 * 128 + m16 * 8;
    for (int ks = 0; ks < K; ks += 32) {
        bf16x8 af[4], wv[4];
        #pragma unroll
        for (int i = 0; i < 4; ++i)
            af[i] = *(const bf16x8*)(Ab + (size_t)(16 * i + m16) * K + ks);
        #pragma unroll
        for (int j = 0; j < 4; ++j)
            wv[j] = *(const bf16x8*)(Wb + (size_t)(j * K8 + (ks >> 3) + quad) * 128);
        #pragma unroll
        for (int i = 0; i < 4; ++i)
            #pragma unroll
            for (int j = 0; j < 4; ++j)
                acc[i][j] = __builtin_amdgcn_mfma_f32_16x16x32_bf16(wv[j], af[i], acc[i][j], 0, 0, 0);
    }

    // bias per j-tile: 4 consecutive outputs per lane
    float4 bj[4];
    #pragma unroll
    for (int j = 0; j < 4; ++j)
        bj[j] = *(const float4*)&bias[o0 + 16 * j + quad * 4];

    #pragma unroll
    for (int p = 0; p < 2; ++p) {
        // stage tiles i = 2p, 2p+1 (32 tokens) into Cw[token][out]
        #pragma unroll
        for (int ih = 0; ih < 2; ++ih) {
            const int i = 2 * p + ih;
            #pragma unroll
            for (int j = 0; j < 4; ++j) {
                f32x4 v = acc[i][j];
                v[0] += bj[j].x; v[1] += bj[j].y; v[2] += bj[j].z; v[3] += bj[j].w;
                if (epi == 2) {
                    #pragma unroll
                    for (int r = 0; r < 4; ++r) {
                        // tanh-GELU via v_rcp (error << bf16 rounding)
                        float xg = v[r];
                        float e1 = __expf(xg * (1.5957691f + 0.0713548f * xg * xg)) + 1.0f;
                        v[r] = xg - xg * __builtin_amdgcn_rcpf(e1);
                    }
                }
                *(f32x4*)&Cw[ih * 16 + m16][16 * j + quad * 4] = v;
            }
        }
        // wave-local LDS: compiler inserts the needed lgkmcnt waits
        if (epi == 2 || epi == 3) {
            #pragma unroll
            for (int q = 0; q < 4; ++q) {
                const int idx = q * 64 + lane;       // 32 rows x 8 chunks
                const int row = idx >> 3, c8 = (idx & 7) * 8;
                float4 f0 = *(const float4*)&Cw[row][c8];
                float4 f1 = *(const float4*)&Cw[row][c8 + 4];
                uint4 w;
                w.x = pk2(f0.x, f0.y); w.y = pk2(f0.z, f0.w);
                w.z = pk2(f1.x, f1.y); w.w = pk2(f1.z, f1.w);
                *(uint4*)&outh[(size_t)(t0 + p * 32 + row) * N + o0 + c8] = w;
            }
        } else if (epi == 4) {
            const int b   = t0 >> 12;
            const int hw0 = t0 & 4095;
            #pragma unroll
            for (int q = 0; q < 8; ++q) {
                const int idx = q * 64 + lane;       // 64 cols x 8 tok4-groups
                const int c = idx >> 3, t4 = (idx & 7) * 4;
                const int tb = t0 + p * 32 + t4;
                float4 vv;
                vv.x = Cw[t4 + 0][c] + res[(size_t)(tb + 0) * N + o0 + c];
                vv.y = Cw[t4 + 1][c] + res[(size_t)(tb + 1) * N + o0 + c];
                vv.z = Cw[t4 + 2][c] + res[(size_t)(tb + 2) * N + o0 + c];
                vv.w = Cw[t4 + 3][c] + res[(size_t)(tb + 3) * N + o0 + c];
                *(float4*)&outf[(size_t)b * (DIM * 4096) + (size_t)(o0 + c) * 4096
                                + (hw0 & 4095) + p * 32 + t4] = vv;
            }
        } else {
            #pragma unroll
            for (int q = 0; q < 8; ++q) {
                const int idx = q * 64 + lane;       // 32 rows x 16 float4
                const int row = idx >> 4, c4 = (idx & 15) * 4;
                float4 vv = *(const float4*)&Cw[row][c4];
                const size_t gidx = (size_t)(t0 + p * 32 + row) * N + o0 + c4;
                if (epi == 1) {
                    const float4 rv = *(const float4*)&res[gidx];
                    vv.x += rv.x; vv.y += rv.y; vv.z += rv.z; vv.w += rv.w;
                }
                *(float4*)&outf[gidx] = vv;
            }
        }
    }
}

// ---------------------------------------------------------------------------
// Kernel 3: windowed cosine attention, bf16 qkv input, ~15.7 KB LDS.
__global__ __launch_bounds__(64) void attn_mfma_kernel(
    const ushort_t* __restrict__ qkvh, const float* __restrict__ rpb_table,
    const float* __restrict__ temp, ushort_t* __restrict__ outb)
{
    __shared__ __align__(16) char smem[16016];
    ushort_t* Qh  = (ushort_t*)smem;
    ushort_t* Kh  = (ushort_t*)(smem + 5120);
    float*    Ss  = (float*)smem;
    ushort_t* Pl  = (ushort_t*)smem;
    ushort_t* Vt  = (ushort_t*)(smem + 10240);
    float*    ksb = (float*)(smem + 14848);
    float*    rpb = (float*)(smem + 15104);

    const int n   = threadIdx.x;
    const int win = blockIdx.x;
    const int h   = blockIdx.y;
    const int b   = win >> 6;
    const int wh  = (win >> 3) & 7, ww = win & 7;
    const int i1  = n >> 3, j1 = n & 7;
    const int t   = b * 4096 + (wh * 8 + i1) * 64 + (ww * 8 + j1);
    const ushort_t* base = qkvh + (size_t)t * 576 + h * 32;
    const int m16 = n & 15, quad = n >> 4;

    unsigned qu[16], ku[16], vu[16];
    #pragma unroll
    for (int c = 0; c < 4; ++c) {
        ((uint4*)qu)[c] = *(const uint4*)(base + 8 * c);
        ((uint4*)ku)[c] = *(const uint4*)(base + 192 + 8 * c);
        ((uint4*)vu)[c] = *(const uint4*)(base + 384 + 8 * c);
    }
    float sq = 0.f, sk = 0.f;
    #pragma unroll
    for (int c = 0; c < 16; ++c) {
        float a0 = __uint_as_float(qu[c] << 16);
        float a1 = __uint_as_float(qu[c] & 0xffff0000u);
        sq += a0 * a0 + a1 * a1;
        float b0 = __uint_as_float(ku[c] << 16);
        float b1 = __uint_as_float(ku[c] & 0xffff0000u);
        sk += b0 * b0 + b1 * b1;
    }
    const float qs  = temp[h] / fmaxf(sqrtf(sq), 1e-12f);
    const float ksc = 1.0f / fmaxf(sqrtf(sk), 1e-12f);

    #pragma unroll
    for (int c = 0; c < 4; ++c) {
        *(uint4*)&Qh[n * 40 + 8 * c] = ((uint4*)qu)[c];
        *(uint4*)&Kh[n * 40 + 8 * c] = ((uint4*)ku)[c];
    }
    const int vslot = 4 * m16 + quad;    // slot(m) = 4*(m&15) + (m>>4)
    #pragma unroll
    for (int d = 0; d < 16; ++d) {
        Vt[(2 * d) * 72 + vslot]     = (ushort_t)(vu[d] & 0xffffu);
        Vt[(2 * d + 1) * 72 + vslot] = (ushort_t)(vu[d] >> 16);
    }
    ksb[vslot] = ksc;
    for (int r = n; r < 225; r += 64) rpb[r] = rpb_table[r * 6 + h];
    __syncthreads();

    bf16x8 aq[4], bk[4];
    #pragma unroll
    for (int i = 0; i < 4; ++i) aq[i] = *(const bf16x8*)&Qh[(16*i + m16) * 40 + quad * 8];
    #pragma unroll
    for (int j = 0; j < 4; ++j) bk[j] = *(const bf16x8*)&Kh[(16*j + m16) * 40 + quad * 8];
    f32x4 acc[4][4];
    #pragma unroll
    for (int i = 0; i < 4; ++i)
        #pragma unroll
        for (int j = 0; j < 4; ++j)
            acc[i][j] = __builtin_amdgcn_mfma_f32_16x16x32_bf16(aq[i], bk[j], (f32x4)(0.0f), 0, 0, 0);
    __syncthreads();

    float s[64];
    #pragma unroll
    for (int i = 0; i < 2; ++i)
        #pragma unroll
        for (int r = 0; r < 4; ++r) {
            f32x4 vv = { acc[i][0][r], acc[i][1][r], acc[i][2][r], acc[i][3][r] };
            *(f32x4*)&Ss[(16 * i + 4 * quad + r) * 68 + 4 * m16] = vv;
        }
    __syncthreads();
    if (n < 32) {
        #pragma unroll
        for (int c = 0; c < 16; ++c)
            *(float4*)&s[4 * c] = *(const float4*)&Ss[n * 68 + 4 * c];
    }
    __syncthreads();
    #pragma unroll
    for (int i = 2; i < 4; ++i)
        #pragma unroll
        for (int r = 0; r < 4; ++r) {
            f32x4 vv = { acc[i][0][r], acc[i][1][r], acc[i][2][r], acc[i][3][r] };
            *(f32x4*)&Ss[(16 * (i - 2) + 4 * quad + r) * 68 + 4 * m16] = vv;
        }
    __syncthreads();
    if (n >= 32) {
        #pragma unroll
        for (int c = 0; c < 16; ++c)
            *(float4*)&s[4 * c] = *(const float4*)&Ss[(n - 32) * 68 + 4 * c];
    }

    #pragma unroll
    for (int c = 0; c < 16; ++c) {
        float4 kv = *(const float4*)&ksb[4 * c];
        s[4*c+0] *= qs * kv.x; s[4*c+1] *= qs * kv.y;
        s[4*c+2] *= qs * kv.z; s[4*c+3] *= qs * kv.w;
    }

    float thr = 1e30f;
    for (int it = 0; it < IN_CC; ++it) {
        float mx = -1e30f;
        #pragma unroll
        for (int m = 0; m < 64; ++m) {
            float vv = (s[m] < thr) ? s[m] : -1e30f;
            mx = fmaxf(mx, vv);
        }
        thr = mx;
    }

    const int basen = i1 * 15 + j1;
    float mx = -1e30f;
    #pragma unroll
    for (int c = 0; c < 64; ++c) {
        const int m = 16 * (c & 3) + (c >> 2);
        const int i2 = m >> 3, j2 = m & 7;
        float vv = ((s[c] >= thr) ? s[c] : -100.0f)
                 + rpb[basen + (7 - i2) * 15 + (7 - j2)];
        s[c] = vv;
        mx = fmaxf(mx, vv);
    }
    float sum = 0.f;
    #pragma unroll
    for (int c = 0; c < 64; ++c) { float e = __expf(s[c] - mx); s[c] = e; sum += e; }
    const float inv = 1.0f / sum;
    #pragma unroll
    for (int c = 0; c < 64; ++c) s[c] *= inv;

    __syncthreads();
    #pragma unroll
    for (int gix = 0; gix < 8; ++gix) {
        uint4 w;
        w.x = pk2(s[8*gix+0], s[8*gix+1]); w.y = pk2(s[8*gix+2], s[8*gix+3]);
        w.z = pk2(s[8*gix+4], s[8*gix+5]); w.w = pk2(s[8*gix+6], s[8*gix+7]);
        *(uint4*)&Pl[n * 72 + 8 * gix] = w;
    }
    __syncthreads();

    f32x4 o[4][2];
    #pragma unroll
    for (int i = 0; i < 4; ++i)
        #pragma unroll
        for (int j2 = 0; j2 < 2; ++j2)
            o[i][j2] = (f32x4)(0.0f);
    #pragma unroll
    for (int kh = 0; kh < 64; kh += 32) {
        bf16x8 pa[4], vb[2];
        #pragma unroll
        for (int i = 0; i < 4; ++i)
            pa[i] = *(const bf16x8*)&Pl[(16*i + m16) * 72 + kh + quad * 8];
        #pragma unroll
        for (int j2 = 0; j2 < 2; ++j2)
            vb[j2] = *(const bf16x8*)&Vt[(16*j2 + m16) * 72 + kh + quad * 8];
        #pragma unroll
        for (int i = 0; i < 4; ++i)
            #pragma unroll
            for (int j2 = 0; j2 < 2; ++j2)
                o[i][j2] = __builtin_amdgcn_mfma_f32_16x16x32_bf16(pa[i], vb[j2], o[i][j2], 0, 0, 0);
    }

    #pragma unroll
    for (int i = 0; i < 4; ++i) {
        #pragma unroll
        for (int r = 0; r < 4; ++r) {
            const int row = 16 * i + 4 * quad + r;
            const int tt  = b * 4096 + (wh * 8 + (row >> 3)) * 64 + ww * 8 + (row & 7);
            ushort_t* op = outb + (size_t)tt * DIM + h * 32;
            op[m16]      = f2b(o[i][0][r]);
            op[m16 + 16] = f2b(o[i][1][r]);
        }
    }
}

// ---------------------------------------------------------------------------
// Kernel 5: LayerNorm2 over (T,192) -> bf16. 1 wave per token (4/block).
__global__ __launch_bounds__(256) void ln2_kernel(
    const float* __restrict__ xin, const float* __restrict__ g,
    const float* __restrict__ bb, ushort_t* __restrict__ outp)
{
    const int tid = threadIdx.x;
    const int t = blockIdx.x * 4 + (tid >> 6);
    const int l = tid & 63;
    const float* rp = xin + (size_t)t * DIM;
    const float v0 = rp[l], v1 = rp[l + 64], v2 = rp[l + 128];
    float sum = v0 + v1 + v2;
    #pragma unroll
    for (int off = 1; off < 64; off <<= 1) sum += __shfl_xor(sum, off);
    const float m = sum * (1.0f / 192.0f);
    const float d0 = v0 - m, d1 = v1 - m, d2 = v2 - m;
    float ss = d0 * d0 + d1 * d1 + d2 * d2;
    #pragma unroll
    for (int off = 1; off < 64; off <<= 1) ss += __shfl_xor(ss, off);
    const float rsg = 1.0f / sqrtf(ss * (1.0f / 192.0f) + 1e-5f);
    ushort_t* op = outp + (size_t)t * DIM;
    op[l]       = f2b(d0 * rsg * g[l]       + bb[l]);
    op[l + 64]  = f2b(d1 * rsg * g[l + 64]  + bb[l + 64]);
    op[l + 128] = f2b(d2 * rsg * g[l + 128] + bb[l + 128]);
}

// ---------------------------------------------------------------------------
extern "C" void kernel_launch(void* const* d_in, const int* in_sizes, int n_in,
                              void* d_out, int out_size, void* d_ws, size_t ws_size,
                              hipStream_t stream)
{
    const float* x        = (const float*)d_in[0];
    const float* norm1_g  = (const float*)d_in[1];
    const float* norm1_b  = (const float*)d_in[2];
    const float* qkv_w    = (const float*)d_in[3];
    const float* qkv_b    = (const float*)d_in[4];
    const float* proj_w   = (const float*)d_in[5];
    const float* proj_b   = (const float*)d_in[6];
    const float* rpbt     = (const float*)d_in[7];
    const float* temp     = (const float*)d_in[8];
    const float* norm2_g  = (const float*)d_in[9];
    const float* norm2_b  = (const float*)d_in[10];
    const float* fc1_w    = (const float*)d_in[11];
    const float* fc1_b    = (const float*)d_in[12];
    const float* fc2_w    = (const float*)d_in[13];
    const float* fc2_b    = (const float*)d_in[14];
    float* out = (float*)d_out;

    // ws layout (bytes):
    //   R0 [0,        25165824)  shortcut f32
    //   R1 [25165824, 37748736)  shortcut bf16 -> hbuf bf16
    //   R2 [37748736, 88080384)  qkvh bf16 (37.7MB) -> a1 bf16 (50.3MB)
    //   R3 [88080384,113246208)  x2 f32
    //   R4 [113246208,125829120) attnout bf16
    //   R5 [125829120,...)       weights bf16 (fragment order)
    char* wsb = (char*)d_ws;
    float*    shortcut   = (float*)wsb;
    ushort_t* shortcut_h = (ushort_t*)(wsb + 25165824);
    ushort_t* qkvh       = (ushort_t*)(wsb + 37748736);
    float*    x2         = (float*)(wsb + 88080384);
    ushort_t* attnout_h  = (ushort_t*)(wsb + 113246208);
    ushort_t* wq  = (ushort_t*)(wsb + 125829120);      // 576x192 = 110592
    ushort_t* wp  = wq + 110592;                       // 192x192 = 36864
    ushort_t* w1  = wp + 36864;                        // 768x192 = 147456
    ushort_t* w2  = w1 + 147456;                       // 192x768 = 147456
    ushort_t* a1    = qkvh;          // reuse R2 (qkvh dead after attn)
    ushort_t* hbuf  = shortcut_h;    // reuse R1

    // 0. merged weight conversions into fragment order, one launch
    hipLaunchKernelGGL(cvt_all_kernel, dim3(432), dim3(256), 0, stream,
                       qkv_w, proj_w, fc1_w, fc2_w, wq, wp, w1, w2);

    // 1. LN1 + transpose -> shortcut f32 + bf16
    hipLaunchKernelGGL(ln1_kernel, dim3(TTOT / 64), dim3(256), 0, stream,
                       x, norm1_g, norm1_b, shortcut, shortcut_h);
    // 2. qkv -> bf16 (epi 3)
    hipLaunchKernelGGL(gemm_mfma, dim3(TTOT / 256, 9), dim3(256), 0, stream,
                       shortcut_h, wq, qkv_b, (const float*)nullptr,
                       (float*)nullptr, qkvh, 576, 192, 3);
    // 3. attention -> attnout bf16
    hipLaunchKernelGGL(attn_mfma_kernel, dim3(NWIN, HEADS), dim3(64), 0, stream,
                       qkvh, rpbt, temp, attnout_h);
    // 4. x2 = attnout @ proj^T + b + shortcut (epi 1)
    hipLaunchKernelGGL(gemm_mfma, dim3(TTOT / 256, 3), dim3(256), 0, stream,
                       attnout_h, wp, proj_b, shortcut,
                       x2, (ushort_t*)nullptr, 192, 192, 1);
    // 5. h = LN2(x2) -> bf16
    hipLaunchKernelGGL(ln2_kernel, dim3(TTOT / 4), dim3(256), 0, stream,
                       x2, norm2_g, norm2_b, hbuf);
    // 6. a1 = gelu(h @ fc1^T + b) -> bf16 (epi 2, rcp-tanh-GELU)
    hipLaunchKernelGGL(gemm_mfma, dim3(TTOT / 256, 12), dim3(256), 0, stream,
                       hbuf, w1, fc1_b, (const float*)nullptr,
                       (float*)nullptr, a1, 768, 192, 2);
    // 7. y = a1 @ fc2^T + b + x2, stored transposed to NCHW out (epi 4)
    hipLaunchKernelGGL(gemm_mfma, dim3(TTOT / 256, 3), dim3(256), 0, stream,
                       a1, w2, fc2_b, x2, out, (ushort_t*)nullptr, 192, 768, 4);
}

// Round 11
// 217.769 us; speedup vs baseline: 1.2069x; 1.2069x over previous
//
#include <hip/hip_runtime.h>
#include <hip/hip_bf16.h>
#include <math.h>

// Problem constants
#define DIM     192
#define HEADS   6
#define HEAD_DIM 32
#define NTOK    64          // tokens per window
#define IN_CC   16
#define TTOT    32768       // 8 * 64 * 64 tokens
#define NWIN    512

using bf16x8 = __attribute__((ext_vector_type(8))) short;
using f32x4  = __attribute__((ext_vector_type(4))) float;
typedef unsigned short ushort_t;

// fp32 -> bf16 round-to-nearest-even (finite inputs)
__device__ __forceinline__ ushort_t f2b(float f) {
    unsigned u = __float_as_uint(f);
    u += 0x7fffu + ((u >> 16) & 1u);
    return (ushort_t)(u >> 16);
}
__device__ __forceinline__ unsigned pk2(float a, float b) {
    return (unsigned)f2b(a) | ((unsigned)f2b(b) << 16);
}

// ---------------------------------------------------------------------------
// Merged weight fp32 -> bf16 conversion INTO MFMA FRAGMENT ORDER.
// W (NxK row-major) -> W' where element (o,k) lives at
//   frag = (o/16)*(K/8) + (k/8);  W'[frag*128 + (o%16)*8 + (k%8)]
__global__ __launch_bounds__(256) void cvt_all_kernel(
    const float* __restrict__ s0, const float* __restrict__ s1,
    const float* __restrict__ s2, const float* __restrict__ s3,
    ushort_t* __restrict__ d0, ushort_t* __restrict__ d1,
    ushort_t* __restrict__ d2, ushort_t* __restrict__ d3)
{
    const int bid = blockIdx.x;
    const float* src; ushort_t* dst; int off, K;
    if (bid < 108)      { src = s0; dst = d0; off = bid;       K = 192; }
    else if (bid < 144) { src = s1; dst = d1; off = bid - 108; K = 192; }
    else if (bid < 288) { src = s2; dst = d2; off = bid - 144; K = 192; }
    else                { src = s3; dst = d3; off = bid - 288; K = 768; }
    const int K8 = K >> 3;
    const int d  = (off * 256 + threadIdx.x) * 4;
    const int frag = d >> 7, win = d & 127;
    const int m16w = win >> 3, k7 = win & 7;
    const int oblk = frag / K8, kblk = frag - oblk * K8;
    const int o = oblk * 16 + m16w, k = kblk * 8 + k7;
    float4 v = *(const float4*)(src + (size_t)o * K + k);
    ushort4 ov;
    ov.x = f2b(v.x); ov.y = f2b(v.y); ov.z = f2b(v.z); ov.w = f2b(v.w);
    *(ushort4*)(dst + d) = ov;
}

// ---------------------------------------------------------------------------
// Kernel 1: LayerNorm1 fused with (B,C,H,W) -> (T,C) transpose.
__global__ __launch_bounds__(256) void ln1_kernel(
    const float* __restrict__ x, const float* __restrict__ g,
    const float* __restrict__ bb, float* __restrict__ outp,
    ushort_t* __restrict__ outh)
{
    __shared__ float xs[64][193];
    __shared__ float mu_s[64], rs_s[64];
    __shared__ float gs[192], bs[192];
    const int tid = threadIdx.x;
    const int t0  = blockIdx.x * 64;
    const int b   = t0 >> 12;
    const int hw0 = t0 & 4095;
    if (tid < 192) { gs[tid] = g[tid]; bs[tid] = bb[tid]; }
    const int tok = tid & 63, qq = tid >> 6;
    const float* xb = x + (size_t)b * (DIM * 4096) + hw0 + tok;
    #pragma unroll
    for (int it = 0; it < 48; ++it) {
        int c = it * 4 + qq;
        xs[tok][c] = xb[(size_t)c * 4096];
    }
    __syncthreads();
    const int tok2 = tid >> 2, p = tid & 3;
    float sum = 0.f;
    #pragma unroll
    for (int c = 0; c < 48; ++c) sum += xs[tok2][p * 48 + c];
    sum += __shfl_xor(sum, 1);
    sum += __shfl_xor(sum, 2);
    const float m = sum * (1.0f / 192.0f);
    float ss = 0.f;
    #pragma unroll
    for (int c = 0; c < 48; ++c) { float d = xs[tok2][p * 48 + c] - m; ss += d * d; }
    ss += __shfl_xor(ss, 1);
    ss += __shfl_xor(ss, 2);
    if (p == 0) {
        mu_s[tok2] = m;
        rs_s[tok2] = 1.0f / sqrtf(ss * (1.0f / 192.0f) + 1e-5f);
    }
    __syncthreads();
    float* ob = outp + (size_t)t0 * DIM;
    ushort_t* obh = outh + (size_t)t0 * DIM;
    #pragma unroll
    for (int it = 0; it < 48; ++it) {
        int idx = it * 256 + tid;
        int tk = idx / 192, c = idx % 192;
        float v = (xs[tk][c] - mu_s[tk]) * rs_s[tk] * gs[c] + bs[c];
        ob[idx] = v;
        obh[idx] = f2b(v);
    }
}

// ---------------------------------------------------------------------------
// Direct-fragment MFMA GEMM (r10-validated), 4 independent waves per block.
// epi: 0=bias->f32, 1=bias+res->f32, 3=bias->bf16
__global__ __launch_bounds__(256) void gemm_mfma(
    const ushort_t* __restrict__ A, const ushort_t* __restrict__ Wf,
    const float* __restrict__ bias, const float* __restrict__ res,
    float* __restrict__ outf, ushort_t* __restrict__ outh,
    int N, int K, int epi)
{
    __shared__ __align__(16) float Ct[4][32][68];
    const int tid  = threadIdx.x;
    const int wave = tid >> 6, lane = tid & 63;
    const int m16 = lane & 15, quad = lane >> 4;
    const int t0 = (blockIdx.x * 4 + wave) * 64, o0 = blockIdx.y * 64;
    const int K8 = K >> 3;
    float (*Cw)[68] = Ct[wave];

    f32x4 acc[4][4];
    #pragma unroll
    for (int i = 0; i < 4; ++i)
        #pragma unroll
        for (int j = 0; j < 4; ++j)
            acc[i][j] = (f32x4)(0.0f);

    const ushort_t* Ab = A + (size_t)t0 * K + quad * 8;
    const ushort_t* Wb = Wf + (size_t)(o0 >> 4) * K8 * 128 + m16 * 8;
    for (int ks = 0; ks < K; ks += 32) {
        bf16x8 af[4], wv[4];
        #pragma unroll
        for (int i = 0; i < 4; ++i)
            af[i] = *(const bf16x8*)(Ab + (size_t)(16 * i + m16) * K + ks);
        #pragma unroll
        for (int j = 0; j < 4; ++j)
            wv[j] = *(const bf16x8*)(Wb + (size_t)(j * K8 + (ks >> 3) + quad) * 128);
        #pragma unroll
        for (int i = 0; i < 4; ++i)
            #pragma unroll
            for (int j = 0; j < 4; ++j)
                acc[i][j] = __builtin_amdgcn_mfma_f32_16x16x32_bf16(wv[j], af[i], acc[i][j], 0, 0, 0);
    }

    float4 bj[4];
    #pragma unroll
    for (int j = 0; j < 4; ++j)
        bj[j] = *(const float4*)&bias[o0 + 16 * j + quad * 4];

    #pragma unroll
    for (int p = 0; p < 2; ++p) {
        #pragma unroll
        for (int ih = 0; ih < 2; ++ih) {
            const int i = 2 * p + ih;
            #pragma unroll
            for (int j = 0; j < 4; ++j) {
                f32x4 v = acc[i][j];
                v[0] += bj[j].x; v[1] += bj[j].y; v[2] += bj[j].z; v[3] += bj[j].w;
                *(f32x4*)&Cw[ih * 16 + m16][16 * j + quad * 4] = v;
            }
        }
        if (epi == 3) {
            #pragma unroll
            for (int q = 0; q < 4; ++q) {
                const int idx = q * 64 + lane;
                const int row = idx >> 3, c8 = (idx & 7) * 8;
                float4 f0 = *(const float4*)&Cw[row][c8];
                float4 f1 = *(const float4*)&Cw[row][c8 + 4];
                uint4 w;
                w.x = pk2(f0.x, f0.y); w.y = pk2(f0.z, f0.w);
                w.z = pk2(f1.x, f1.y); w.w = pk2(f1.z, f1.w);
                *(uint4*)&outh[(size_t)(t0 + p * 32 + row) * N + o0 + c8] = w;
            }
        } else {
            #pragma unroll
            for (int q = 0; q < 8; ++q) {
                const int idx = q * 64 + lane;
                const int row = idx >> 4, c4 = (idx & 15) * 4;
                float4 vv = *(const float4*)&Cw[row][c4];
                const size_t gidx = (size_t)(t0 + p * 32 + row) * N + o0 + c4;
                if (epi == 1) {
                    const float4 rv = *(const float4*)&res[gidx];
                    vv.x += rv.x; vv.y += rv.y; vv.z += rv.z; vv.w += rv.w;
                }
                *(float4*)&outf[gidx] = vv;
            }
        }
    }
}

// ---------------------------------------------------------------------------
// FUSED MLP kernel: per 64-token tile, LN2 -> fc1+GELU (6 chunks of 128
// outputs staged in LDS) -> fc2 accumulated in registers across chunks ->
// +bias +residual(x2) -> transposed store to (B,C,64,64) NCHW.
// a1 never touches global memory. 256 threads = 4 waves.
// LDS: h_h[64][200] bf16 (25.6KB) + a1c[64][136] bf16 (17.4KB) = 43KB;
// epilogue Ct[4][32][68] f32 (34.8KB) overlays (after barrier).
__global__ __launch_bounds__(256) void mlp_fused(
    const float* __restrict__ x2, const ushort_t* __restrict__ w1f,
    const ushort_t* __restrict__ w2f, const float* __restrict__ fc1_b,
    const float* __restrict__ fc2_b, const float* __restrict__ g2,
    const float* __restrict__ b2, float* __restrict__ outp)
{
    __shared__ __align__(16) char smem[43008];
    ushort_t (*h_h)[200] = (ushort_t(*)[200])smem;            // [64][200]
    ushort_t (*a1c)[136] = (ushort_t(*)[136])(smem + 25600);  // [64][136]
    float* gs  = (float*)(smem + 25600);                      // phase-1 only
    float* bs  = gs + 192;

    const int tid  = threadIdx.x;
    const int wave = tid >> 6, lane = tid & 63;
    const int m16 = lane & 15, quad = lane >> 4;
    const int t0 = blockIdx.x * 64;
    const int b   = t0 >> 12;
    const int hw0 = t0 & 4095;

    // ---- phase 1: LN2 of x2 tile -> h_h bf16 ----
    if (tid < 192) { gs[tid] = g2[tid]; bs[tid] = b2[tid]; }
    __syncthreads();
    {
        const int tok = tid >> 2, p = tid & 3;
        const float* rp = x2 + (size_t)(t0 + tok) * DIM + p * 48;
        float xv[48];
        #pragma unroll
        for (int c4 = 0; c4 < 12; ++c4)
            *(float4*)&xv[c4 * 4] = *(const float4*)(rp + c4 * 4);
        float sum = 0.f;
        #pragma unroll
        for (int c = 0; c < 48; ++c) sum += xv[c];
        sum += __shfl_xor(sum, 1);
        sum += __shfl_xor(sum, 2);
        const float m = sum * (1.0f / 192.0f);
        float ss = 0.f;
        #pragma unroll
        for (int c = 0; c < 48; ++c) { float d = xv[c] - m; ss += d * d; }
        ss += __shfl_xor(ss, 1);
        ss += __shfl_xor(ss, 2);
        const float rs = 1.0f / sqrtf(ss * (1.0f / 192.0f) + 1e-5f);
        ushort_t* hp = &h_h[tok][p * 48];
        #pragma unroll
        for (int c2 = 0; c2 < 24; ++c2) {
            float v0 = (xv[2*c2]   - m) * rs * gs[p * 48 + 2*c2]   + bs[p * 48 + 2*c2];
            float v1 = (xv[2*c2+1] - m) * rs * gs[p * 48 + 2*c2+1] + bs[p * 48 + 2*c2+1];
            *(unsigned*)(hp + 2 * c2) = pk2(v0, v1);
        }
    }
    __syncthreads();

    // ---- fc2 accumulator: wave owns outputs [wave*48, wave*48+48) ----
    f32x4 acc2[4][3];
    #pragma unroll
    for (int i = 0; i < 4; ++i)
        #pragma unroll
        for (int j = 0; j < 3; ++j)
            acc2[i][j] = (f32x4)(0.0f);

    // ---- phase 2: 6 chunks of 128 fc1-outputs ----
    for (int c = 0; c < 6; ++c) {
        // fc1 chunk: wave computes outs oc = c*128 + wave*32 .. +32
        f32x4 acc1[4][2];
        #pragma unroll
        for (int i = 0; i < 4; ++i)
            #pragma unroll
            for (int j = 0; j < 2; ++j)
                acc1[i][j] = (f32x4)(0.0f);
        const ushort_t* Wb1 = w1f + (size_t)(c * 8 + wave * 2) * 24 * 128 + m16 * 8;
        for (int ks = 0; ks < 192; ks += 32) {
            bf16x8 af[4], wv[2];
            #pragma unroll
            for (int i = 0; i < 4; ++i)
                af[i] = *(const bf16x8*)&h_h[16 * i + m16][quad * 8 + ks];
            #pragma unroll
            for (int j = 0; j < 2; ++j)
                wv[j] = *(const bf16x8*)(Wb1 + (size_t)(j * 24 + (ks >> 3) + quad) * 128);
            #pragma unroll
            for (int i = 0; i < 4; ++i)
                #pragma unroll
                for (int j = 0; j < 2; ++j)
                    acc1[i][j] = __builtin_amdgcn_mfma_f32_16x16x32_bf16(wv[j], af[i], acc1[i][j], 0, 0, 0);
        }
        // gelu + pack into a1c (C^T: lane's 4 accs are consecutive outputs)
        float2 b1j[2];
        #pragma unroll
        for (int j = 0; j < 2; ++j) {
            const int o = c * 128 + wave * 32 + 16 * j + quad * 4;
            b1j[j] = make_float2(0.f, 0.f);   // placeholder; bias added below via f4
        }
        #pragma unroll
        for (int j = 0; j < 2; ++j) {
            const int o = c * 128 + wave * 32 + 16 * j + quad * 4;
            const float4 bv = *(const float4*)&fc1_b[o];
            #pragma unroll
            for (int i = 0; i < 4; ++i) {
                f32x4 v = acc1[i][j];
                v[0] += bv.x; v[1] += bv.y; v[2] += bv.z; v[3] += bv.w;
                #pragma unroll
                for (int r = 0; r < 4; ++r) {
                    float xg = v[r];
                    float e1 = __expf(xg * (1.5957691f + 0.0713548f * xg * xg)) + 1.0f;
                    v[r] = xg - xg * __builtin_amdgcn_rcpf(e1);
                }
                uint2 pkd;
                pkd.x = pk2(v[0], v[1]); pkd.y = pk2(v[2], v[3]);
                *(uint2*)&a1c[16 * i + m16][wave * 32 + 16 * j + quad * 4] = pkd;
            }
        }
        __syncthreads();
        // fc2 accumulate over this chunk's K=128
        const ushort_t* Wb2 = w2f + (size_t)(wave * 3) * 96 * 128 + m16 * 8;
        for (int ks = 0; ks < 128; ks += 32) {
            bf16x8 af2[4], wv2[3];
            #pragma unroll
            for (int i = 0; i < 4; ++i)
                af2[i] = *(const bf16x8*)&a1c[16 * i + m16][quad * 8 + ks];
            #pragma unroll
            for (int j = 0; j < 3; ++j)
                wv2[j] = *(const bf16x8*)(Wb2 + (size_t)(j * 96 + c * 16 + (ks >> 3) + quad) * 128);
            #pragma unroll
            for (int i = 0; i < 4; ++i)
                #pragma unroll
                for (int j = 0; j < 3; ++j)
                    acc2[i][j] = __builtin_amdgcn_mfma_f32_16x16x32_bf16(wv2[j], af2[i], acc2[i][j], 0, 0, 0);
        }
        __syncthreads();   // a1c reused next chunk
    }

    // ---- epilogue: +bias, +res(x2), transposed NCHW store ----
    float (*Cw)[68] = (float(*)[68])(smem + wave * 8704);   // per-wave slice
    float4 b2j[3];
    #pragma unroll
    for (int j = 0; j < 3; ++j)
        b2j[j] = *(const float4*)&fc2_b[wave * 48 + 16 * j + quad * 4];
    #pragma unroll
    for (int p = 0; p < 2; ++p) {
        #pragma unroll
        for (int ih = 0; ih < 2; ++ih) {
            const int i = 2 * p + ih;
            #pragma unroll
            for (int j = 0; j < 3; ++j) {
                f32x4 v = acc2[i][j];
                v[0] += b2j[j].x; v[1] += b2j[j].y; v[2] += b2j[j].z; v[3] += b2j[j].w;
                *(f32x4*)&Cw[ih * 16 + m16][16 * j + quad * 4] = v;
            }
        }
        // 48 cols x 8 tok4-groups = 384 items over 64 lanes
        #pragma unroll
        for (int q = 0; q < 6; ++q) {
            const int idx = q * 64 + lane;
            const int cc = idx >> 3, t4 = (idx & 7) * 4;
            const int o  = wave * 48 + cc;
            const int tb = t0 + p * 32 + t4;
            float4 vv;
            vv.x = Cw[t4 + 0][cc] + x2[(size_t)(tb + 0) * DIM + o];
            vv.y = Cw[t4 + 1][cc] + x2[(size_t)(tb + 1) * DIM + o];
            vv.z = Cw[t4 + 2][cc] + x2[(size_t)(tb + 2) * DIM + o];
            vv.w = Cw[t4 + 3][cc] + x2[(size_t)(tb + 3) * DIM + o];
            *(float4*)&outp[(size_t)b * (DIM * 4096) + (size_t)o * 4096
                            + hw0 + p * 32 + t4] = vv;
        }
    }
}

// ---------------------------------------------------------------------------
// Kernel 3: windowed cosine attention, bf16 qkv input, ~15.7 KB LDS.
__global__ __launch_bounds__(64) void attn_mfma_kernel(
    const ushort_t* __restrict__ qkvh, const float* __restrict__ rpb_table,
    const float* __restrict__ temp, ushort_t* __restrict__ outb)
{
    __shared__ __align__(16) char smem[16016];
    ushort_t* Qh  = (ushort_t*)smem;
    ushort_t* Kh  = (ushort_t*)(smem + 5120);
    float*    Ss  = (float*)smem;
    ushort_t* Pl  = (ushort_t*)smem;
    ushort_t* Vt  = (ushort_t*)(smem + 10240);
    float*    ksb = (float*)(smem + 14848);
    float*    rpb = (float*)(smem + 15104);

    const int n   = threadIdx.x;
    const int win = blockIdx.x;
    const int h   = blockIdx.y;
    const int b   = win >> 6;
    const int wh  = (win >> 3) & 7, ww = win & 7;
    const int i1  = n >> 3, j1 = n & 7;
    const int t   = b * 4096 + (wh * 8 + i1) * 64 + (ww * 8 + j1);
    const ushort_t* base = qkvh + (size_t)t * 576 + h * 32;
    const int m16 = n & 15, quad = n >> 4;

    unsigned qu[16], ku[16], vu[16];
    #pragma unroll
    for (int c = 0; c < 4; ++c) {
        ((uint4*)qu)[c] = *(const uint4*)(base + 8 * c);
        ((uint4*)ku)[c] = *(const uint4*)(base + 192 + 8 * c);
        ((uint4*)vu)[c] = *(const uint4*)(base + 384 + 8 * c);
    }
    float sq = 0.f, sk = 0.f;
    #pragma unroll
    for (int c = 0; c < 16; ++c) {
        float a0 = __uint_as_float(qu[c] << 16);
        float a1 = __uint_as_float(qu[c] & 0xffff0000u);
        sq += a0 * a0 + a1 * a1;
        float b0 = __uint_as_float(ku[c] << 16);
        float b1 = __uint_as_float(ku[c] & 0xffff0000u);
        sk += b0 * b0 + b1 * b1;
    }
    const float qs  = temp[h] / fmaxf(sqrtf(sq), 1e-12f);
    const float ksc = 1.0f / fmaxf(sqrtf(sk), 1e-12f);

    #pragma unroll
    for (int c = 0; c < 4; ++c) {
        *(uint4*)&Qh[n * 40 + 8 * c] = ((uint4*)qu)[c];
        *(uint4*)&Kh[n * 40 + 8 * c] = ((uint4*)ku)[c];
    }
    const int vslot = 4 * m16 + quad;
    #pragma unroll
    for (int d = 0; d < 16; ++d) {
        Vt[(2 * d) * 72 + vslot]     = (ushort_t)(vu[d] & 0xffffu);
        Vt[(2 * d + 1) * 72 + vslot] = (ushort_t)(vu[d] >> 16);
    }
    ksb[vslot] = ksc;
    for (int r = n; r < 225; r += 64) rpb[r] = rpb_table[r * 6 + h];
    __syncthreads();

    bf16x8 aq[4], bk[4];
    #pragma unroll
    for (int i = 0; i < 4; ++i) aq[i] = *(const bf16x8*)&Qh[(16*i + m16) * 40 + quad * 8];
    #pragma unroll
    for (int j = 0; j < 4; ++j) bk[j] = *(const bf16x8*)&Kh[(16*j + m16) * 40 + quad * 8];
    f32x4 acc[4][4];
    #pragma unroll
    for (int i = 0; i < 4; ++i)
        #pragma unroll
        for (int j = 0; j < 4; ++j)
            acc[i][j] = __builtin_amdgcn_mfma_f32_16x16x32_bf16(aq[i], bk[j], (f32x4)(0.0f), 0, 0, 0);
    __syncthreads();

    float s[64];
    #pragma unroll
    for (int i = 0; i < 2; ++i)
        #pragma unroll
        for (int r = 0; r < 4; ++r) {
            f32x4 vv = { acc[i][0][r], acc[i][1][r], acc[i][2][r], acc[i][3][r] };
            *(f32x4*)&Ss[(16 * i + 4 * quad + r) * 68 + 4 * m16] = vv;
        }
    __syncthreads();
    if (n < 32) {
        #pragma unroll
        for (int c = 0; c < 16; ++c)
            *(float4*)&s[4 * c] = *(const float4*)&Ss[n * 68 + 4 * c];
    }
    __syncthreads();
    #pragma unroll
    for (int i = 2; i < 4; ++i)
        #pragma unroll
        for (int r = 0; r < 4; ++r) {
            f32x4 vv = { acc[i][0][r], acc[i][1][r], acc[i][2][r], acc[i][3][r] };
            *(f32x4*)&Ss[(16 * (i - 2) + 4 * quad + r) * 68 + 4 * m16] = vv;
        }
    __syncthreads();
    if (n >= 32) {
        #pragma unroll
        for (int c = 0; c < 16; ++c)
            *(float4*)&s[4 * c] = *(const float4*)&Ss[(n - 32) * 68 + 4 * c];
    }

    #pragma unroll
    for (int c = 0; c < 16; ++c) {
        float4 kv = *(const float4*)&ksb[4 * c];
        s[4*c+0] *= qs * kv.x; s[4*c+1] *= qs * kv.y;
        s[4*c+2] *= qs * kv.z; s[4*c+3] *= qs * kv.w;
    }

    float thr = 1e30f;
    for (int it = 0; it < IN_CC; ++it) {
        float mx = -1e30f;
        #pragma unroll
        for (int m = 0; m < 64; ++m) {
            float vv = (s[m] < thr) ? s[m] : -1e30f;
            mx = fmaxf(mx, vv);
        }
        thr = mx;
    }

    const int basen = i1 * 15 + j1;
    float mx = -1e30f;
    #pragma unroll
    for (int c = 0; c < 64; ++c) {
        const int m = 16 * (c & 3) + (c >> 2);
        const int i2 = m >> 3, j2 = m & 7;
        float vv = ((s[c] >= thr) ? s[c] : -100.0f)
                 + rpb[basen + (7 - i2) * 15 + (7 - j2)];
        s[c] = vv;
        mx = fmaxf(mx, vv);
    }
    float sum = 0.f;
    #pragma unroll
    for (int c = 0; c < 64; ++c) { float e = __expf(s[c] - mx); s[c] = e; sum += e; }
    const float inv = 1.0f / sum;
    #pragma unroll
    for (int c = 0; c < 64; ++c) s[c] *= inv;

    __syncthreads();
    #pragma unroll
    for (int gix = 0; gix < 8; ++gix) {
        uint4 w;
        w.x = pk2(s[8*gix+0], s[8*gix+1]); w.y = pk2(s[8*gix+2], s[8*gix+3]);
        w.z = pk2(s[8*gix+4], s[8*gix+5]); w.w = pk2(s[8*gix+6], s[8*gix+7]);
        *(uint4*)&Pl[n * 72 + 8 * gix] = w;
    }
    __syncthreads();

    f32x4 o[4][2];
    #pragma unroll
    for (int i = 0; i < 4; ++i)
        #pragma unroll
        for (int j2 = 0; j2 < 2; ++j2)
            o[i][j2] = (f32x4)(0.0f);
    #pragma unroll
    for (int kh = 0; kh < 64; kh += 32) {
        bf16x8 pa[4], vb[2];
        #pragma unroll
        for (int i = 0; i < 4; ++i)
            pa[i] = *(const bf16x8*)&Pl[(16*i + m16) * 72 + kh + quad * 8];
        #pragma unroll
        for (int j2 = 0; j2 < 2; ++j2)
            vb[j2] = *(const bf16x8*)&Vt[(16*j2 + m16) * 72 + kh + quad * 8];
        #pragma unroll
        for (int i = 0; i < 4; ++i)
            #pragma unroll
            for (int j2 = 0; j2 < 2; ++j2)
                o[i][j2] = __builtin_amdgcn_mfma_f32_16x16x32_bf16(pa[i], vb[j2], o[i][j2], 0, 0, 0);
    }

    #pragma unroll
    for (int i = 0; i < 4; ++i) {
        #pragma unroll
        for (int r = 0; r < 4; ++r) {
            const int row = 16 * i + 4 * quad + r;
            const int tt  = b * 4096 + (wh * 8 + (row >> 3)) * 64 + ww * 8 + (row & 7);
            ushort_t* op = outb + (size_t)tt * DIM + h * 32;
            op[m16]      = f2b(o[i][0][r]);
            op[m16 + 16] = f2b(o[i][1][r]);
        }
    }
}

// ---------------------------------------------------------------------------
extern "C" void kernel_launch(void* const* d_in, const int* in_sizes, int n_in,
                              void* d_out, int out_size, void* d_ws, size_t ws_size,
                              hipStream_t stream)
{
    const float* x        = (const float*)d_in[0];
    const float* norm1_g  = (const float*)d_in[1];
    const float* norm1_b  = (const float*)d_in[2];
    const float* qkv_w    = (const float*)d_in[3];
    const float* qkv_b    = (const float*)d_in[4];
    const float* proj_w   = (const float*)d_in[5];
    const float* proj_b   = (const float*)d_in[6];
    const float* rpbt     = (const float*)d_in[7];
    const float* temp     = (const float*)d_in[8];
    const float* norm2_g  = (const float*)d_in[9];
    const float* norm2_b  = (const float*)d_in[10];
    const float* fc1_w    = (const float*)d_in[11];
    const float* fc1_b    = (const float*)d_in[12];
    const float* fc2_w    = (const float*)d_in[13];
    const float* fc2_b    = (const float*)d_in[14];
    float* out = (float*)d_out;

    // ws layout (bytes):
    //   R0 [0,        25165824)  shortcut f32
    //   R1 [25165824, 37748736)  shortcut bf16
    //   R2 [37748736, 88080384)  qkvh bf16 (37.7MB)
    //   R3 [88080384,113246208)  x2 f32
    //   R4 [113246208,125829120) attnout bf16
    //   R5 [125829120,...)       weights bf16 (fragment order)
    char* wsb = (char*)d_ws;
    float*    shortcut   = (float*)wsb;
    ushort_t* shortcut_h = (ushort_t*)(wsb + 25165824);
    ushort_t* qkvh       = (ushort_t*)(wsb + 37748736);
    float*    x2         = (float*)(wsb + 88080384);
    ushort_t* attnout_h  = (ushort_t*)(wsb + 113246208);
    ushort_t* wq  = (ushort_t*)(wsb + 125829120);      // 576x192 = 110592
    ushort_t* wp  = wq + 110592;                       // 192x192 = 36864
    ushort_t* w1  = wp + 36864;                        // 768x192 = 147456
    ushort_t* w2  = w1 + 147456;                       // 192x768 = 147456

    // 0. merged weight conversions into fragment order, one launch
    hipLaunchKernelGGL(cvt_all_kernel, dim3(432), dim3(256), 0, stream,
                       qkv_w, proj_w, fc1_w, fc2_w, wq, wp, w1, w2);

    // 1. LN1 + transpose -> shortcut f32 + bf16
    hipLaunchKernelGGL(ln1_kernel, dim3(TTOT / 64), dim3(256), 0, stream,
                       x, norm1_g, norm1_b, shortcut, shortcut_h);
    // 2. qkv -> bf16 (epi 3)
    hipLaunchKernelGGL(gemm_mfma, dim3(TTOT / 256, 9), dim3(256), 0, stream,
                       shortcut_h, wq, qkv_b, (const float*)nullptr,
                       (float*)nullptr, qkvh, 576, 192, 3);
    // 3. attention -> attnout bf16
    hipLaunchKernelGGL(attn_mfma_kernel, dim3(NWIN, HEADS), dim3(64), 0, stream,
                       qkvh, rpbt, temp, attnout_h);
    // 4. x2 = attnout @ proj^T + b + shortcut (epi 1)
    hipLaunchKernelGGL(gemm_mfma, dim3(TTOT / 256, 3), dim3(256), 0, stream,
                       attnout_h, wp, proj_b, shortcut,
                       x2, (ushort_t*)nullptr, 192, 192, 1);
    // 5-7. fused LN2 + fc1 + GELU + fc2 + residual + NCHW transpose
    hipLaunchKernelGGL(mlp_fused, dim3(TTOT / 64), dim3(256), 0, stream,
                       x2, w1, w2, fc1_b, fc2_b, norm2_g, norm2_b, out);
}

// Round 12
// 217.331 us; speedup vs baseline: 1.2093x; 1.0020x over previous
//
#include <hip/hip_runtime.h>
#include <hip/hip_bf16.h>
#include <math.h>

// Problem constants
#define DIM     192
#define HEADS   6
#define HEAD_DIM 32
#define NTOK    64          // tokens per window
#define IN_CC   16
#define TTOT    32768       // 8 * 64 * 64 tokens
#define NWIN    512

using bf16x8 = __attribute__((ext_vector_type(8))) short;
using f32x4  = __attribute__((ext_vector_type(4))) float;
typedef unsigned short ushort_t;

// fp32 -> bf16 round-to-nearest-even (finite inputs)
__device__ __forceinline__ ushort_t f2b(float f) {
    unsigned u = __float_as_uint(f);
    u += 0x7fffu + ((u >> 16) & 1u);
    return (ushort_t)(u >> 16);
}
__device__ __forceinline__ unsigned pk2(float a, float b) {
    return (unsigned)f2b(a) | ((unsigned)f2b(b) << 16);
}

// ---------------------------------------------------------------------------
// Merged weight fp32 -> bf16 conversion INTO MFMA FRAGMENT ORDER.
// W (NxK row-major) -> W' where element (o,k) lives at
//   frag = (o/16)*(K/8) + (k/8);  W'[frag*128 + (o%16)*8 + (k%8)]
__global__ __launch_bounds__(256) void cvt_all_kernel(
    const float* __restrict__ s0, const float* __restrict__ s1,
    const float* __restrict__ s2, const float* __restrict__ s3,
    ushort_t* __restrict__ d0, ushort_t* __restrict__ d1,
    ushort_t* __restrict__ d2, ushort_t* __restrict__ d3)
{
    const int bid = blockIdx.x;
    const float* src; ushort_t* dst; int off, K;
    if (bid < 108)      { src = s0; dst = d0; off = bid;       K = 192; }
    else if (bid < 144) { src = s1; dst = d1; off = bid - 108; K = 192; }
    else if (bid < 288) { src = s2; dst = d2; off = bid - 144; K = 192; }
    else                { src = s3; dst = d3; off = bid - 288; K = 768; }
    const int K8 = K >> 3;
    const int d  = (off * 256 + threadIdx.x) * 4;
    const int frag = d >> 7, win = d & 127;
    const int m16w = win >> 3, k7 = win & 7;
    const int oblk = frag / K8, kblk = frag - oblk * K8;
    const int o = oblk * 16 + m16w, k = kblk * 8 + k7;
    float4 v = *(const float4*)(src + (size_t)o * K + k);
    ushort4 ov;
    ov.x = f2b(v.x); ov.y = f2b(v.y); ov.z = f2b(v.z); ov.w = f2b(v.w);
    *(ushort4*)(dst + d) = ov;
}

// ---------------------------------------------------------------------------
// Kernel 1: LayerNorm1 fused with (B,C,H,W) -> (T,C) transpose.
__global__ __launch_bounds__(256) void ln1_kernel(
    const float* __restrict__ x, const float* __restrict__ g,
    const float* __restrict__ bb, float* __restrict__ outp,
    ushort_t* __restrict__ outh)
{
    __shared__ float xs[64][193];
    __shared__ float mu_s[64], rs_s[64];
    __shared__ float gs[192], bs[192];
    const int tid = threadIdx.x;
    const int t0  = blockIdx.x * 64;
    const int b   = t0 >> 12;
    const int hw0 = t0 & 4095;
    if (tid < 192) { gs[tid] = g[tid]; bs[tid] = bb[tid]; }
    const int tok = tid & 63, qq = tid >> 6;
    const float* xb = x + (size_t)b * (DIM * 4096) + hw0 + tok;
    #pragma unroll
    for (int it = 0; it < 48; ++it) {
        int c = it * 4 + qq;
        xs[tok][c] = xb[(size_t)c * 4096];
    }
    __syncthreads();
    const int tok2 = tid >> 2, p = tid & 3;
    float sum = 0.f;
    #pragma unroll
    for (int c = 0; c < 48; ++c) sum += xs[tok2][p * 48 + c];
    sum += __shfl_xor(sum, 1);
    sum += __shfl_xor(sum, 2);
    const float m = sum * (1.0f / 192.0f);
    float ss = 0.f;
    #pragma unroll
    for (int c = 0; c < 48; ++c) { float d = xs[tok2][p * 48 + c] - m; ss += d * d; }
    ss += __shfl_xor(ss, 1);
    ss += __shfl_xor(ss, 2);
    if (p == 0) {
        mu_s[tok2] = m;
        rs_s[tok2] = 1.0f / sqrtf(ss * (1.0f / 192.0f) + 1e-5f);
    }
    __syncthreads();
    float* ob = outp + (size_t)t0 * DIM;
    ushort_t* obh = outh + (size_t)t0 * DIM;
    #pragma unroll
    for (int it = 0; it < 48; ++it) {
        int idx = it * 256 + tid;
        int tk = idx / 192, c = idx % 192;
        float v = (xs[tk][c] - mu_s[tk]) * rs_s[tk] * gs[c] + bs[c];
        ob[idx] = v;
        obh[idx] = f2b(v);
    }
}

// ---------------------------------------------------------------------------
// Direct-fragment MFMA GEMM (r10-validated), 4 independent waves per block.
// Used only for qkv now. epi 3 = bias->bf16.
__global__ __launch_bounds__(256) void gemm_mfma(
    const ushort_t* __restrict__ A, const ushort_t* __restrict__ Wf,
    const float* __restrict__ bias, const float* __restrict__ res,
    float* __restrict__ outf, ushort_t* __restrict__ outh,
    int N, int K, int epi)
{
    __shared__ __align__(16) float Ct[4][32][68];
    const int tid  = threadIdx.x;
    const int wave = tid >> 6, lane = tid & 63;
    const int m16 = lane & 15, quad = lane >> 4;
    const int t0 = (blockIdx.x * 4 + wave) * 64, o0 = blockIdx.y * 64;
    const int K8 = K >> 3;
    float (*Cw)[68] = Ct[wave];

    f32x4 acc[4][4];
    #pragma unroll
    for (int i = 0; i < 4; ++i)
        #pragma unroll
        for (int j = 0; j < 4; ++j)
            acc[i][j] = (f32x4)(0.0f);

    const ushort_t* Ab = A + (size_t)t0 * K + quad * 8;
    const ushort_t* Wb = Wf + (size_t)(o0 >> 4) * K8 * 128 + m16 * 8;
    for (int ks = 0; ks < K; ks += 32) {
        bf16x8 af[4], wv[4];
        #pragma unroll
        for (int i = 0; i < 4; ++i)
            af[i] = *(const bf16x8*)(Ab + (size_t)(16 * i + m16) * K + ks);
        #pragma unroll
        for (int j = 0; j < 4; ++j)
            wv[j] = *(const bf16x8*)(Wb + (size_t)(j * K8 + (ks >> 3) + quad) * 128);
        #pragma unroll
        for (int i = 0; i < 4; ++i)
            #pragma unroll
            for (int j = 0; j < 4; ++j)
                acc[i][j] = __builtin_amdgcn_mfma_f32_16x16x32_bf16(wv[j], af[i], acc[i][j], 0, 0, 0);
    }

    float4 bj[4];
    #pragma unroll
    for (int j = 0; j < 4; ++j)
        bj[j] = *(const float4*)&bias[o0 + 16 * j + quad * 4];

    #pragma unroll
    for (int p = 0; p < 2; ++p) {
        #pragma unroll
        for (int ih = 0; ih < 2; ++ih) {
            const int i = 2 * p + ih;
            #pragma unroll
            for (int j = 0; j < 4; ++j) {
                f32x4 v = acc[i][j];
                v[0] += bj[j].x; v[1] += bj[j].y; v[2] += bj[j].z; v[3] += bj[j].w;
                *(f32x4*)&Cw[ih * 16 + m16][16 * j + quad * 4] = v;
            }
        }
        if (epi == 3) {
            #pragma unroll
            for (int q = 0; q < 4; ++q) {
                const int idx = q * 64 + lane;
                const int row = idx >> 3, c8 = (idx & 7) * 8;
                float4 f0 = *(const float4*)&Cw[row][c8];
                float4 f1 = *(const float4*)&Cw[row][c8 + 4];
                uint4 w;
                w.x = pk2(f0.x, f0.y); w.y = pk2(f0.z, f0.w);
                w.z = pk2(f1.x, f1.y); w.w = pk2(f1.z, f1.w);
                *(uint4*)&outh[(size_t)(t0 + p * 32 + row) * N + o0 + c8] = w;
            }
        } else {
            #pragma unroll
            for (int q = 0; q < 8; ++q) {
                const int idx = q * 64 + lane;
                const int row = idx >> 4, c4 = (idx & 15) * 4;
                float4 vv = *(const float4*)&Cw[row][c4];
                const size_t gidx = (size_t)(t0 + p * 32 + row) * N + o0 + c4;
                if (epi == 1) {
                    const float4 rv = *(const float4*)&res[gidx];
                    vv.x += rv.x; vv.y += rv.y; vv.z += rv.z; vv.w += rv.w;
                }
                *(float4*)&outf[gidx] = vv;
            }
        }
    }
}

// ---------------------------------------------------------------------------
// FUSED attention + proj: one block per window, 6 waves (wave = head).
// Each wave runs the r4-validated attention body in its own 16128 B LDS
// arena (block barriers are phase-uniform across waves). O then goes to a
// shared 64x200 bf16 tile (overlays dead arenas), and the same waves compute
// proj (64x32 outputs each, K=192) + bias + shortcut residual -> x2.
// attnout never touches global memory.
__global__ __launch_bounds__(384) void attn_proj_fused(
    const ushort_t* __restrict__ qkvh, const float* __restrict__ rpb_table,
    const float* __restrict__ temp, const ushort_t* __restrict__ wpf,
    const float* __restrict__ proj_b, const float* __restrict__ shortcut,
    float* __restrict__ x2)
{
    __shared__ __align__(16) char smem[96768];   // 6 arenas of 16128 B
    const int tid  = threadIdx.x;
    const int wave = tid >> 6, n = tid & 63;
    char* arena = smem + wave * 16128;
    ushort_t* Qh  = (ushort_t*)arena;            // [64][40]
    ushort_t* Kh  = (ushort_t*)(arena + 5120);
    float*    Ss  = (float*)arena;               // [32][68]
    ushort_t* Pl  = (ushort_t*)arena;            // [64][72]
    ushort_t* Vt  = (ushort_t*)(arena + 10240);  // [32][72]
    float*    ksb = (float*)(arena + 14848);
    float*    rpb = (float*)(arena + 15104);
    ushort_t (*AoT)[200] = (ushort_t(*)[200])smem;          // 25600 B
    float* Cww = (float*)(smem + 25600 + wave * 9216);      // [64][36] f32

    const int win = blockIdx.x;
    const int h   = wave;
    const int b   = win >> 6;
    const int wh  = (win >> 3) & 7, ww = win & 7;
    const int i1  = n >> 3, j1 = n & 7;
    const int t   = b * 4096 + (wh * 8 + i1) * 64 + (ww * 8 + j1);
    const ushort_t* base = qkvh + (size_t)t * 576 + h * 32;
    const int m16 = n & 15, quad = n >> 4;

    // ---- load raw bf16 q,k,v ----
    unsigned qu[16], ku[16], vu[16];
    #pragma unroll
    for (int c = 0; c < 4; ++c) {
        ((uint4*)qu)[c] = *(const uint4*)(base + 8 * c);
        ((uint4*)ku)[c] = *(const uint4*)(base + 192 + 8 * c);
        ((uint4*)vu)[c] = *(const uint4*)(base + 384 + 8 * c);
    }
    float sq = 0.f, sk = 0.f;
    #pragma unroll
    for (int c = 0; c < 16; ++c) {
        float a0 = __uint_as_float(qu[c] << 16);
        float a1 = __uint_as_float(qu[c] & 0xffff0000u);
        sq += a0 * a0 + a1 * a1;
        float b0 = __uint_as_float(ku[c] << 16);
        float b1 = __uint_as_float(ku[c] & 0xffff0000u);
        sk += b0 * b0 + b1 * b1;
    }
    const float qs  = temp[h] / fmaxf(sqrtf(sq), 1e-12f);
    const float ksc = 1.0f / fmaxf(sqrtf(sk), 1e-12f);

    #pragma unroll
    for (int c = 0; c < 4; ++c) {
        *(uint4*)&Qh[n * 40 + 8 * c] = ((uint4*)qu)[c];
        *(uint4*)&Kh[n * 40 + 8 * c] = ((uint4*)ku)[c];
    }
    const int vslot = 4 * m16 + quad;    // slot(m) = 4*(m&15) + (m>>4)
    #pragma unroll
    for (int d = 0; d < 16; ++d) {
        Vt[(2 * d) * 72 + vslot]     = (ushort_t)(vu[d] & 0xffffu);
        Vt[(2 * d + 1) * 72 + vslot] = (ushort_t)(vu[d] >> 16);
    }
    ksb[vslot] = ksc;
    for (int r = n; r < 225; r += 64) rpb[r] = rpb_table[r * 6 + h];
    __syncthreads();

    // ---- raw QK^T via MFMA ----
    bf16x8 aq[4], bk[4];
    #pragma unroll
    for (int i = 0; i < 4; ++i) aq[i] = *(const bf16x8*)&Qh[(16*i + m16) * 40 + quad * 8];
    #pragma unroll
    for (int j = 0; j < 4; ++j) bk[j] = *(const bf16x8*)&Kh[(16*j + m16) * 40 + quad * 8];
    f32x4 acc[4][4];
    #pragma unroll
    for (int i = 0; i < 4; ++i)
        #pragma unroll
        for (int j = 0; j < 4; ++j)
            acc[i][j] = __builtin_amdgcn_mfma_f32_16x16x32_bf16(aq[i], bk[j], (f32x4)(0.0f), 0, 0, 0);
    __syncthreads();

    // ---- transpose S via 32-row half-buffer ----
    float s[64];
    #pragma unroll
    for (int i = 0; i < 2; ++i)
        #pragma unroll
        for (int r = 0; r < 4; ++r) {
            f32x4 vv = { acc[i][0][r], acc[i][1][r], acc[i][2][r], acc[i][3][r] };
            *(f32x4*)&Ss[(16 * i + 4 * quad + r) * 68 + 4 * m16] = vv;
        }
    __syncthreads();
    if (n < 32) {
        #pragma unroll
        for (int c = 0; c < 16; ++c)
            *(float4*)&s[4 * c] = *(const float4*)&Ss[n * 68 + 4 * c];
    }
    __syncthreads();
    #pragma unroll
    for (int i = 2; i < 4; ++i)
        #pragma unroll
        for (int r = 0; r < 4; ++r) {
            f32x4 vv = { acc[i][0][r], acc[i][1][r], acc[i][2][r], acc[i][3][r] };
            *(f32x4*)&Ss[(16 * (i - 2) + 4 * quad + r) * 68 + 4 * m16] = vv;
        }
    __syncthreads();
    if (n >= 32) {
        #pragma unroll
        for (int c = 0; c < 16; ++c)
            *(float4*)&s[4 * c] = *(const float4*)&Ss[(n - 32) * 68 + 4 * c];
    }

    #pragma unroll
    for (int c = 0; c < 16; ++c) {
        float4 kv = *(const float4*)&ksb[4 * c];
        s[4*c+0] *= qs * kv.x; s[4*c+1] *= qs * kv.y;
        s[4*c+2] *= qs * kv.z; s[4*c+3] *= qs * kv.w;
    }

    // ---- top-16 threshold ----
    float thr = 1e30f;
    for (int it = 0; it < IN_CC; ++it) {
        float mx = -1e30f;
        #pragma unroll
        for (int m = 0; m < 64; ++m) {
            float vv = (s[m] < thr) ? s[m] : -1e30f;
            mx = fmaxf(mx, vv);
        }
        thr = mx;
    }

    // ---- mask + rpb + softmax ----
    const int basen = i1 * 15 + j1;
    float mx = -1e30f;
    #pragma unroll
    for (int c = 0; c < 64; ++c) {
        const int m = 16 * (c & 3) + (c >> 2);
        const int i2 = m >> 3, j2 = m & 7;
        float vv = ((s[c] >= thr) ? s[c] : -100.0f)
                 + rpb[basen + (7 - i2) * 15 + (7 - j2)];
        s[c] = vv;
        mx = fmaxf(mx, vv);
    }
    float sum = 0.f;
    #pragma unroll
    for (int c = 0; c < 64; ++c) { float e = __expf(s[c] - mx); s[c] = e; sum += e; }
    const float inv = 1.0f / sum;
    #pragma unroll
    for (int c = 0; c < 64; ++c) s[c] *= inv;

    __syncthreads();
    #pragma unroll
    for (int gix = 0; gix < 8; ++gix) {
        uint4 w;
        w.x = pk2(s[8*gix+0], s[8*gix+1]); w.y = pk2(s[8*gix+2], s[8*gix+3]);
        w.z = pk2(s[8*gix+4], s[8*gix+5]); w.w = pk2(s[8*gix+6], s[8*gix+7]);
        *(uint4*)&Pl[n * 72 + 8 * gix] = w;
    }
    __syncthreads();

    // ---- PV via MFMA ----
    f32x4 o[4][2];
    #pragma unroll
    for (int i = 0; i < 4; ++i)
        #pragma unroll
        for (int j2 = 0; j2 < 2; ++j2)
            o[i][j2] = (f32x4)(0.0f);
    #pragma unroll
    for (int kh = 0; kh < 64; kh += 32) {
        bf16x8 pa[4], vb[2];
        #pragma unroll
        for (int i = 0; i < 4; ++i)
            pa[i] = *(const bf16x8*)&Pl[(16*i + m16) * 72 + kh + quad * 8];
        #pragma unroll
        for (int j2 = 0; j2 < 2; ++j2)
            vb[j2] = *(const bf16x8*)&Vt[(16*j2 + m16) * 72 + kh + quad * 8];
        #pragma unroll
        for (int i = 0; i < 4; ++i)
            #pragma unroll
            for (int j2 = 0; j2 < 2; ++j2)
                o[i][j2] = __builtin_amdgcn_mfma_f32_16x16x32_bf16(pa[i], vb[j2], o[i][j2], 0, 0, 0);
    }
    __syncthreads();   // all arenas dead -> AoT may overlay

    // ---- O -> shared AoT tile (bf16, token-major, stride 200) ----
    #pragma unroll
    for (int i = 0; i < 4; ++i) {
        #pragma unroll
        for (int r = 0; r < 4; ++r) {
            const int row = 16 * i + 4 * quad + r;
            AoT[row][h * 32 + m16]      = f2b(o[i][0][r]);
            AoT[row][h * 32 + 16 + m16] = f2b(o[i][1][r]);
        }
    }
    __syncthreads();

    // ---- proj: wave computes outs [wave*32, wave*32+32), K=192 ----
    f32x4 pacc[4][2];
    #pragma unroll
    for (int i = 0; i < 4; ++i)
        #pragma unroll
        for (int j = 0; j < 2; ++j)
            pacc[i][j] = (f32x4)(0.0f);
    const ushort_t* Wb = wpf + (size_t)(wave * 2) * 24 * 128 + m16 * 8;
    for (int ks = 0; ks < 192; ks += 32) {
        bf16x8 af[4], wv[2];
        #pragma unroll
        for (int i = 0; i < 4; ++i)
            af[i] = *(const bf16x8*)&AoT[16 * i + m16][quad * 8 + ks];
        #pragma unroll
        for (int j = 0; j < 2; ++j)
            wv[j] = *(const bf16x8*)(Wb + (size_t)(j * 24 + (ks >> 3) + quad) * 128);
        #pragma unroll
        for (int i = 0; i < 4; ++i)
            #pragma unroll
            for (int j = 0; j < 2; ++j)
                pacc[i][j] = __builtin_amdgcn_mfma_f32_16x16x32_bf16(wv[j], af[i], pacc[i][j], 0, 0, 0);
    }

    // ---- stage C^T (+bias) into per-wave Cww[64][36] ----
    float4 bj[2];
    #pragma unroll
    for (int j = 0; j < 2; ++j)
        bj[j] = *(const float4*)&proj_b[wave * 32 + 16 * j + quad * 4];
    #pragma unroll
    for (int i = 0; i < 4; ++i)
        #pragma unroll
        for (int j = 0; j < 2; ++j) {
            f32x4 v = pacc[i][j];
            v[0] += bj[j].x; v[1] += bj[j].y; v[2] += bj[j].z; v[3] += bj[j].w;
            *(f32x4*)&Cww[(16 * i + m16) * 36 + 16 * j + quad * 4] = v;
        }
    // wave-local Cww: no barrier needed

    // ---- store x2 = proj + shortcut (window-scattered rows, float4 cols) ----
    #pragma unroll
    for (int q = 0; q < 8; ++q) {
        const int idx = q * 64 + n;
        const int row = idx >> 3, c4 = (idx & 7) * 4;
        const int ii = row >> 3, jj = row & 7;
        const int tt = b * 4096 + (wh * 8 + ii) * 64 + ww * 8 + jj;
        float4 vv = *(const float4*)&Cww[row * 36 + c4];
        const float4 rv = *(const float4*)&shortcut[(size_t)tt * DIM + wave * 32 + c4];
        vv.x += rv.x; vv.y += rv.y; vv.z += rv.z; vv.w += rv.w;
        *(float4*)&x2[(size_t)tt * DIM + wave * 32 + c4] = vv;
    }
}

// ---------------------------------------------------------------------------
// FUSED MLP kernel (r11-validated): LN2 -> fc1+GELU -> fc2 -> +res -> NCHW.
__global__ __launch_bounds__(256) void mlp_fused(
    const float* __restrict__ x2, const ushort_t* __restrict__ w1f,
    const ushort_t* __restrict__ w2f, const float* __restrict__ fc1_b,
    const float* __restrict__ fc2_b, const float* __restrict__ g2,
    const float* __restrict__ b2, float* __restrict__ outp)
{
    __shared__ __align__(16) char smem[43008];
    ushort_t (*h_h)[200] = (ushort_t(*)[200])smem;            // [64][200]
    ushort_t (*a1c)[136] = (ushort_t(*)[136])(smem + 25600);  // [64][136]
    float* gs  = (float*)(smem + 25600);                      // phase-1 only
    float* bs  = gs + 192;

    const int tid  = threadIdx.x;
    const int wave = tid >> 6, lane = tid & 63;
    const int m16 = lane & 15, quad = lane >> 4;
    const int t0 = blockIdx.x * 64;
    const int b   = t0 >> 12;
    const int hw0 = t0 & 4095;

    if (tid < 192) { gs[tid] = g2[tid]; bs[tid] = b2[tid]; }
    __syncthreads();
    {
        const int tok = tid >> 2, p = tid & 3;
        const float* rp = x2 + (size_t)(t0 + tok) * DIM + p * 48;
        float xv[48];
        #pragma unroll
        for (int c4 = 0; c4 < 12; ++c4)
            *(float4*)&xv[c4 * 4] = *(const float4*)(rp + c4 * 4);
        float sum = 0.f;
        #pragma unroll
        for (int c = 0; c < 48; ++c) sum += xv[c];
        sum += __shfl_xor(sum, 1);
        sum += __shfl_xor(sum, 2);
        const float m = sum * (1.0f / 192.0f);
        float ss = 0.f;
        #pragma unroll
        for (int c = 0; c < 48; ++c) { float d = xv[c] - m; ss += d * d; }
        ss += __shfl_xor(ss, 1);
        ss += __shfl_xor(ss, 2);
        const float rs = 1.0f / sqrtf(ss * (1.0f / 192.0f) + 1e-5f);
        ushort_t* hp = &h_h[tok][p * 48];
        #pragma unroll
        for (int c2 = 0; c2 < 24; ++c2) {
            float v0 = (xv[2*c2]   - m) * rs * gs[p * 48 + 2*c2]   + bs[p * 48 + 2*c2];
            float v1 = (xv[2*c2+1] - m) * rs * gs[p * 48 + 2*c2+1] + bs[p * 48 + 2*c2+1];
            *(unsigned*)(hp + 2 * c2) = pk2(v0, v1);
        }
    }
    __syncthreads();

    f32x4 acc2[4][3];
    #pragma unroll
    for (int i = 0; i < 4; ++i)
        #pragma unroll
        for (int j = 0; j < 3; ++j)
            acc2[i][j] = (f32x4)(0.0f);

    for (int c = 0; c < 6; ++c) {
        f32x4 acc1[4][2];
        #pragma unroll
        for (int i = 0; i < 4; ++i)
            #pragma unroll
            for (int j = 0; j < 2; ++j)
                acc1[i][j] = (f32x4)(0.0f);
        const ushort_t* Wb1 = w1f + (size_t)(c * 8 + wave * 2) * 24 * 128 + m16 * 8;
        for (int ks = 0; ks < 192; ks += 32) {
            bf16x8 af[4], wv[2];
            #pragma unroll
            for (int i = 0; i < 4; ++i)
                af[i] = *(const bf16x8*)&h_h[16 * i + m16][quad * 8 + ks];
            #pragma unroll
            for (int j = 0; j < 2; ++j)
                wv[j] = *(const bf16x8*)(Wb1 + (size_t)(j * 24 + (ks >> 3) + quad) * 128);
            #pragma unroll
            for (int i = 0; i < 4; ++i)
                #pragma unroll
                for (int j = 0; j < 2; ++j)
                    acc1[i][j] = __builtin_amdgcn_mfma_f32_16x16x32_bf16(wv[j], af[i], acc1[i][j], 0, 0, 0);
        }
        #pragma unroll
        for (int j = 0; j < 2; ++j) {
            const int o = c * 128 + wave * 32 + 16 * j + quad * 4;
            const float4 bv = *(const float4*)&fc1_b[o];
            #pragma unroll
            for (int i = 0; i < 4; ++i) {
                f32x4 v = acc1[i][j];
                v[0] += bv.x; v[1] += bv.y; v[2] += bv.z; v[3] += bv.w;
                #pragma unroll
                for (int r = 0; r < 4; ++r) {
                    float xg = v[r];
                    float e1 = __expf(xg * (1.5957691f + 0.0713548f * xg * xg)) + 1.0f;
                    v[r] = xg - xg * __builtin_amdgcn_rcpf(e1);
                }
                uint2 pkd;
                pkd.x = pk2(v[0], v[1]); pkd.y = pk2(v[2], v[3]);
                *(uint2*)&a1c[16 * i + m16][wave * 32 + 16 * j + quad * 4] = pkd;
            }
        }
        __syncthreads();
        const ushort_t* Wb2 = w2f + (size_t)(wave * 3) * 96 * 128 + m16 * 8;
        for (int ks = 0; ks < 128; ks += 32) {
            bf16x8 af2[4], wv2[3];
            #pragma unroll
            for (int i = 0; i < 4; ++i)
                af2[i] = *(const bf16x8*)&a1c[16 * i + m16][quad * 8 + ks];
            #pragma unroll
            for (int j = 0; j < 3; ++j)
                wv2[j] = *(const bf16x8*)(Wb2 + (size_t)(j * 96 + c * 16 + (ks >> 3) + quad) * 128);
            #pragma unroll
            for (int i = 0; i < 4; ++i)
                #pragma unroll
                for (int j = 0; j < 3; ++j)
                    acc2[i][j] = __builtin_amdgcn_mfma_f32_16x16x32_bf16(wv2[j], af2[i], acc2[i][j], 0, 0, 0);
        }
        __syncthreads();
    }

    float (*Cw)[68] = (float(*)[68])(smem + wave * 8704);
    float4 b2j[3];
    #pragma unroll
    for (int j = 0; j < 3; ++j)
        b2j[j] = *(const float4*)&fc2_b[wave * 48 + 16 * j + quad * 4];
    #pragma unroll
    for (int p = 0; p < 2; ++p) {
        #pragma unroll
        for (int ih = 0; ih < 2; ++ih) {
            const int i = 2 * p + ih;
            #pragma unroll
            for (int j = 0; j < 3; ++j) {
                f32x4 v = acc2[i][j];
                v[0] += b2j[j].x; v[1] += b2j[j].y; v[2] += b2j[j].z; v[3] += b2j[j].w;
                *(f32x4*)&Cw[ih * 16 + m16][16 * j + quad * 4] = v;
            }
        }
        #pragma unroll
        for (int q = 0; q < 6; ++q) {
            const int idx = q * 64 + lane;
            const int cc = idx >> 3, t4 = (idx & 7) * 4;
            const int o  = wave * 48 + cc;
            const int tb = t0 + p * 32 + t4;
            float4 vv;
            vv.x = Cw[t4 + 0][cc] + x2[(size_t)(tb + 0) * DIM + o];
            vv.y = Cw[t4 + 1][cc] + x2[(size_t)(tb + 1) * DIM + o];
            vv.z = Cw[t4 + 2][cc] + x2[(size_t)(tb + 2) * DIM + o];
            vv.w = Cw[t4 + 3][cc] + x2[(size_t)(tb + 3) * DIM + o];
            *(float4*)&outp[(size_t)b * (DIM * 4096) + (size_t)o * 4096
                            + hw0 + p * 32 + t4] = vv;
        }
    }
}

// ---------------------------------------------------------------------------
extern "C" void kernel_launch(void* const* d_in, const int* in_sizes, int n_in,
                              void* d_out, int out_size, void* d_ws, size_t ws_size,
                              hipStream_t stream)
{
    const float* x        = (const float*)d_in[0];
    const float* norm1_g  = (const float*)d_in[1];
    const float* norm1_b  = (const float*)d_in[2];
    const float* qkv_w    = (const float*)d_in[3];
    const float* qkv_b    = (const float*)d_in[4];
    const float* proj_w   = (const float*)d_in[5];
    const float* proj_b   = (const float*)d_in[6];
    const float* rpbt     = (const float*)d_in[7];
    const float* temp     = (const float*)d_in[8];
    const float* norm2_g  = (const float*)d_in[9];
    const float* norm2_b  = (const float*)d_in[10];
    const float* fc1_w    = (const float*)d_in[11];
    const float* fc1_b    = (const float*)d_in[12];
    const float* fc2_w    = (const float*)d_in[13];
    const float* fc2_b    = (const float*)d_in[14];
    float* out = (float*)d_out;

    // ws layout (bytes):
    //   R0 [0,        25165824)  shortcut f32
    //   R1 [25165824, 37748736)  shortcut bf16
    //   R2 [37748736, 88080384)  qkvh bf16 (37.7MB)
    //   R3 [88080384,113246208)  x2 f32
    //   R5 [125829120,...)       weights bf16 (fragment order)
    char* wsb = (char*)d_ws;
    float*    shortcut   = (float*)wsb;
    ushort_t* shortcut_h = (ushort_t*)(wsb + 25165824);
    ushort_t* qkvh       = (ushort_t*)(wsb + 37748736);
    float*    x2         = (float*)(wsb + 88080384);
    ushort_t* wq  = (ushort_t*)(wsb + 125829120);      // 576x192 = 110592
    ushort_t* wp  = wq + 110592;                       // 192x192 = 36864
    ushort_t* w1  = wp + 36864;                        // 768x192 = 147456
    ushort_t* w2  = w1 + 147456;                       // 192x768 = 147456

    // 0. merged weight conversions into fragment order, one launch
    hipLaunchKernelGGL(cvt_all_kernel, dim3(432), dim3(256), 0, stream,
                       qkv_w, proj_w, fc1_w, fc2_w, wq, wp, w1, w2);

    // 1. LN1 + transpose -> shortcut f32 + bf16
    hipLaunchKernelGGL(ln1_kernel, dim3(TTOT / 64), dim3(256), 0, stream,
                       x, norm1_g, norm1_b, shortcut, shortcut_h);
    // 2. qkv -> bf16 (epi 3)
    hipLaunchKernelGGL(gemm_mfma, dim3(TTOT / 256, 9), dim3(256), 0, stream,
                       shortcut_h, wq, qkv_b, (const float*)nullptr,
                       (float*)nullptr, qkvh, 576, 192, 3);
    // 3+4. fused attention + proj + residual -> x2
    hipLaunchKernelGGL(attn_proj_fused, dim3(NWIN), dim3(384), 0, stream,
                       qkvh, rpbt, temp, wp, proj_b, shortcut, x2);
    // 5-7. fused LN2 + fc1 + GELU + fc2 + residual + NCHW transpose
    hipLaunchKernelGGL(mlp_fused, dim3(TTOT / 64), dim3(256), 0, stream,
                       x2, w1, w2, fc1_b, fc2_b, norm2_g, norm2_b, out);
}

// Round 13
// 212.049 us; speedup vs baseline: 1.2394x; 1.0249x over previous
//
#include <hip/hip_runtime.h>
#include <hip/hip_bf16.h>
#include <math.h>

// Problem constants
#define DIM     192
#define HEADS   6
#define HEAD_DIM 32
#define NTOK    64          // tokens per window
#define IN_CC   16
#define TTOT    32768       // 8 * 64 * 64 tokens
#define NWIN    512

using bf16x8 = __attribute__((ext_vector_type(8))) short;
using f32x4  = __attribute__((ext_vector_type(4))) float;
typedef unsigned short ushort_t;

// fp32 -> bf16 round-to-nearest-even (finite inputs)
__device__ __forceinline__ ushort_t f2b(float f) {
    unsigned u = __float_as_uint(f);
    u += 0x7fffu + ((u >> 16) & 1u);
    return (ushort_t)(u >> 16);
}
__device__ __forceinline__ unsigned pk2(float a, float b) {
    return (unsigned)f2b(a) | ((unsigned)f2b(b) << 16);
}
__device__ __forceinline__ float b2f(ushort_t u) {
    return __uint_as_float(((unsigned)u) << 16);
}

// ---------------------------------------------------------------------------
// Merged weight fp32 -> bf16 conversion INTO MFMA FRAGMENT ORDER.
// W (NxK row-major) -> W' where element (o,k) lives at
//   frag = (o/16)*(K/8) + (k/8);  W'[frag*128 + (o%16)*8 + (k%8)]
__global__ __launch_bounds__(256) void cvt_all_kernel(
    const float* __restrict__ s0, const float* __restrict__ s1,
    const float* __restrict__ s2, const float* __restrict__ s3,
    ushort_t* __restrict__ d0, ushort_t* __restrict__ d1,
    ushort_t* __restrict__ d2, ushort_t* __restrict__ d3)
{
    const int bid = blockIdx.x;
    const float* src; ushort_t* dst; int off, K;
    if (bid < 108)      { src = s0; dst = d0; off = bid;       K = 192; }
    else if (bid < 144) { src = s1; dst = d1; off = bid - 108; K = 192; }
    else if (bid < 288) { src = s2; dst = d2; off = bid - 144; K = 192; }
    else                { src = s3; dst = d3; off = bid - 288; K = 768; }
    const int K8 = K >> 3;
    const int d  = (off * 256 + threadIdx.x) * 4;
    const int frag = d >> 7, win = d & 127;
    const int m16w = win >> 3, k7 = win & 7;
    const int oblk = frag / K8, kblk = frag - oblk * K8;
    const int o = oblk * 16 + m16w, k = kblk * 8 + k7;
    float4 v = *(const float4*)(src + (size_t)o * K + k);
    ushort4 ov;
    ov.x = f2b(v.x); ov.y = f2b(v.y); ov.z = f2b(v.z); ov.w = f2b(v.w);
    *(ushort4*)(dst + d) = ov;
}

// ---------------------------------------------------------------------------
// Kernel 1: LayerNorm1 fused with (B,C,H,W) -> (T,C) transpose. bf16 out only.
__global__ __launch_bounds__(256) void ln1_kernel(
    const float* __restrict__ x, const float* __restrict__ g,
    const float* __restrict__ bb, ushort_t* __restrict__ outh)
{
    __shared__ float xs[64][193];
    __shared__ float mu_s[64], rs_s[64];
    __shared__ float gs[192], bs[192];
    const int tid = threadIdx.x;
    const int t0  = blockIdx.x * 64;
    const int b   = t0 >> 12;
    const int hw0 = t0 & 4095;
    if (tid < 192) { gs[tid] = g[tid]; bs[tid] = bb[tid]; }
    const int tok = tid & 63, qq = tid >> 6;
    const float* xb = x + (size_t)b * (DIM * 4096) + hw0 + tok;
    #pragma unroll
    for (int it = 0; it < 48; ++it) {
        int c = it * 4 + qq;
        xs[tok][c] = xb[(size_t)c * 4096];
    }
    __syncthreads();
    const int tok2 = tid >> 2, p = tid & 3;
    float sum = 0.f;
    #pragma unroll
    for (int c = 0; c < 48; ++c) sum += xs[tok2][p * 48 + c];
    sum += __shfl_xor(sum, 1);
    sum += __shfl_xor(sum, 2);
    const float m = sum * (1.0f / 192.0f);
    float ss = 0.f;
    #pragma unroll
    for (int c = 0; c < 48; ++c) { float d = xs[tok2][p * 48 + c] - m; ss += d * d; }
    ss += __shfl_xor(ss, 1);
    ss += __shfl_xor(ss, 2);
    if (p == 0) {
        mu_s[tok2] = m;
        rs_s[tok2] = 1.0f / sqrtf(ss * (1.0f / 192.0f) + 1e-5f);
    }
    __syncthreads();
    ushort_t* obh = outh + (size_t)t0 * DIM;
    #pragma unroll
    for (int it = 0; it < 48; ++it) {
        int idx = it * 256 + tid;
        int tk = idx / 192, c = idx % 192;
        obh[idx] = f2b((xs[tk][c] - mu_s[tk]) * rs_s[tk] * gs[c] + bs[c]);
    }
}

// ---------------------------------------------------------------------------
// MEGA-FUSED attention: per window (block), 6 waves (wave = head).
// Each wave: qkv GEMMs (64x32 x3, K=192, from shortcut bf16 + frag-order wq)
// into its PRIVATE arena -> QK^T -> top-16 -> softmax -> PV -> (barrier)
// O to shared AoT -> proj + bias + bf16-shortcut residual -> x2.
// qkvh/attnout never touch global. Wave-private phases have NO barriers
// (in-order per-wave LDS pipe; r7-r11 validated pattern).
__global__ __launch_bounds__(384) void attn_fused(
    const ushort_t* __restrict__ sc_h, const ushort_t* __restrict__ wqf,
    const float* __restrict__ qkv_b, const float* __restrict__ rpb_table,
    const float* __restrict__ temp, const ushort_t* __restrict__ wpf,
    const float* __restrict__ proj_b, float* __restrict__ x2)
{
    __shared__ __align__(16) char smem[98304];   // 6 arenas x 16384 B
    const int tid  = threadIdx.x;
    const int wave = tid >> 6, n = tid & 63;
    char* arena = smem + wave * 16384;
    ushort_t* Qh  = (ushort_t*)arena;            // [64][40] raw q (w/ bias)
    ushort_t* Kh  = (ushort_t*)(arena + 5120);   // [64][40]
    float*    Ss  = (float*)arena;               // [32][68] overlay
    ushort_t* Pl  = (ushort_t*)arena;            // [64][72] overlay
    ushort_t* Vt  = (ushort_t*)(arena + 10240);  // [32][72] V^T slot-permuted
    float*    ksb = (float*)(arena + 14848);     // [64] slot-ordered 1/||k||
    float*    qnb = (float*)(arena + 15104);     // [64] ssq of q per token
    float*    rpb = (float*)(arena + 15360);     // [225]
    ushort_t (*AoT)[200] = (ushort_t(*)[200])smem;          // 25600 B overlay
    float* Cww = (float*)(smem + 25600 + wave * 9216);      // [64][36] f32

    const int win = blockIdx.x;
    const int h   = wave;
    const int b   = win >> 6;
    const int wh  = (win >> 3) & 7, ww = win & 7;
    const int i1  = n >> 3, j1 = n & 7;
    const int m16 = n & 15, quad = n >> 4;

    for (int r = n; r < 225; r += 64) rpb[r] = rpb_table[r * 6 + h];

    // token rows this lane covers as MFMA A-row m16 (window-scattered)
    int trow[4];
    #pragma unroll
    for (int i = 0; i < 4; ++i) {
        const int row = 16 * i + m16;
        trow[i] = b * 4096 + (wh * 8 + (row >> 3)) * 64 + ww * 8 + (row & 7);
    }

    // ---- phase 1: q, k, v GEMMs into private arena (C^T layout) ----
    #pragma unroll
    for (int part = 0; part < 3; ++part) {       // 0=q, 1=k, 2=v
        const int o0 = part * 192 + h * 32;
        f32x4 pa[4][2];
        #pragma unroll
        for (int i = 0; i < 4; ++i)
            #pragma unroll
            for (int j = 0; j < 2; ++j)
                pa[i][j] = (f32x4)(0.0f);
        const ushort_t* Wb = wqf + (size_t)(o0 >> 4) * 24 * 128 + m16 * 8;
        for (int ks = 0; ks < 192; ks += 32) {
            bf16x8 af[4], wv[2];
            #pragma unroll
            for (int i = 0; i < 4; ++i)
                af[i] = *(const bf16x8*)(sc_h + (size_t)trow[i] * 192 + ks + quad * 8);
            #pragma unroll
            for (int j = 0; j < 2; ++j)
                wv[j] = *(const bf16x8*)(Wb + (size_t)(j * 24 + (ks >> 3) + quad) * 128);
            #pragma unroll
            for (int i = 0; i < 4; ++i)
                #pragma unroll
                for (int j = 0; j < 2; ++j)
                    pa[i][j] = __builtin_amdgcn_mfma_f32_16x16x32_bf16(wv[j], af[i], pa[i][j], 0, 0, 0);
        }
        float4 bv0 = *(const float4*)&qkv_b[o0 + quad * 4];
        float4 bv1 = *(const float4*)&qkv_b[o0 + 16 + quad * 4];
        float ssq[4] = {0.f, 0.f, 0.f, 0.f};
        #pragma unroll
        for (int i = 0; i < 4; ++i) {
            f32x4 v0 = pa[i][0], v1 = pa[i][1];
            v0[0] += bv0.x; v0[1] += bv0.y; v0[2] += bv0.z; v0[3] += bv0.w;
            v1[0] += bv1.x; v1[1] += bv1.y; v1[2] += bv1.z; v1[3] += bv1.w;
            if (part < 2) {
                #pragma unroll
                for (int r = 0; r < 4; ++r)
                    ssq[i] += v0[r] * v0[r] + v1[r] * v1[r];
                ushort_t* dst = (part == 0) ? Qh : Kh;
                uint2 w0, w1;
                w0.x = pk2(v0[0], v0[1]); w0.y = pk2(v0[2], v0[3]);
                w1.x = pk2(v1[0], v1[1]); w1.y = pk2(v1[2], v1[3]);
                *(uint2*)&dst[(16 * i + m16) * 40 + quad * 4]      = w0;
                *(uint2*)&dst[(16 * i + m16) * 40 + 16 + quad * 4] = w1;
            } else {
                #pragma unroll
                for (int r = 0; r < 4; ++r) {
                    Vt[(quad * 4 + r) * 72 + 4 * m16 + i]      = f2b(v0[r]);
                    Vt[(16 + quad * 4 + r) * 72 + 4 * m16 + i] = f2b(v1[r]);
                }
            }
        }
        if (part < 2) {
            #pragma unroll
            for (int i = 0; i < 4; ++i) {
                ssq[i] += __shfl_xor(ssq[i], 16);
                ssq[i] += __shfl_xor(ssq[i], 32);
            }
            if (quad == 0) {
                #pragma unroll
                for (int i = 0; i < 4; ++i) {
                    if (part == 0) qnb[16 * i + m16] = ssq[i];
                    else           ksb[4 * m16 + i]  = 1.0f / fmaxf(sqrtf(ssq[i]), 1e-12f);
                }
            }
        }
    }
    // all arena data wave-private; per-wave in-order LDS pipe -> no barrier

    // ---- phase 2: QK^T (raw) ----
    bf16x8 aq[4], bk[4];
    #pragma unroll
    for (int i = 0; i < 4; ++i) aq[i] = *(const bf16x8*)&Qh[(16*i + m16) * 40 + quad * 8];
    #pragma unroll
    for (int j = 0; j < 4; ++j) bk[j] = *(const bf16x8*)&Kh[(16*j + m16) * 40 + quad * 8];
    f32x4 acc[4][4];
    #pragma unroll
    for (int i = 0; i < 4; ++i)
        #pragma unroll
        for (int j = 0; j < 4; ++j)
            acc[i][j] = __builtin_amdgcn_mfma_f32_16x16x32_bf16(aq[i], bk[j], (f32x4)(0.0f), 0, 0, 0);

    // ---- transpose S via 32-row half-buffer (wave-local) ----
    float s[64];
    #pragma unroll
    for (int i = 0; i < 2; ++i)
        #pragma unroll
        for (int r = 0; r < 4; ++r) {
            f32x4 vv = { acc[i][0][r], acc[i][1][r], acc[i][2][r], acc[i][3][r] };
            *(f32x4*)&Ss[(16 * i + 4 * quad + r) * 68 + 4 * m16] = vv;
        }
    if (n < 32) {
        #pragma unroll
        for (int c = 0; c < 16; ++c)
            *(float4*)&s[4 * c] = *(const float4*)&Ss[n * 68 + 4 * c];
    }
    #pragma unroll
    for (int i = 2; i < 4; ++i)
        #pragma unroll
        for (int r = 0; r < 4; ++r) {
            f32x4 vv = { acc[i][0][r], acc[i][1][r], acc[i][2][r], acc[i][3][r] };
            *(f32x4*)&Ss[(16 * (i - 2) + 4 * quad + r) * 68 + 4 * m16] = vv;
        }
    if (n >= 32) {
        #pragma unroll
        for (int c = 0; c < 16; ++c)
            *(float4*)&s[4 * c] = *(const float4*)&Ss[(n - 32) * 68 + 4 * c];
    }

    // ---- cosine scales (positive; preserve top-k ordering) ----
    const float qs = temp[h] / fmaxf(sqrtf(qnb[n]), 1e-12f);
    #pragma unroll
    for (int c = 0; c < 16; ++c) {
        float4 kv = *(const float4*)&ksb[4 * c];
        s[4*c+0] *= qs * kv.x; s[4*c+1] *= qs * kv.y;
        s[4*c+2] *= qs * kv.z; s[4*c+3] *= qs * kv.w;
    }

    // ---- top-16 threshold ----
    float thr = 1e30f;
    for (int it = 0; it < IN_CC; ++it) {
        float mx = -1e30f;
        #pragma unroll
        for (int m = 0; m < 64; ++m) {
            float vv = (s[m] < thr) ? s[m] : -1e30f;
            mx = fmaxf(mx, vv);
        }
        thr = mx;
    }

    // ---- mask + rpb + softmax (slot c holds true m = 16*(c&3)+(c>>2)) ----
    const int basen = i1 * 15 + j1;
    float mx = -1e30f;
    #pragma unroll
    for (int c = 0; c < 64; ++c) {
        const int m = 16 * (c & 3) + (c >> 2);
        const int i2 = m >> 3, j2 = m & 7;
        float vv = ((s[c] >= thr) ? s[c] : -100.0f)
                 + rpb[basen + (7 - i2) * 15 + (7 - j2)];
        s[c] = vv;
        mx = fmaxf(mx, vv);
    }
    float sum = 0.f;
    #pragma unroll
    for (int c = 0; c < 64; ++c) { float e = __expf(s[c] - mx); s[c] = e; sum += e; }
    const float inv = 1.0f / sum;
    #pragma unroll
    for (int c = 0; c < 64; ++c) s[c] *= inv;

    #pragma unroll
    for (int gix = 0; gix < 8; ++gix) {
        uint4 w;
        w.x = pk2(s[8*gix+0], s[8*gix+1]); w.y = pk2(s[8*gix+2], s[8*gix+3]);
        w.z = pk2(s[8*gix+4], s[8*gix+5]); w.w = pk2(s[8*gix+6], s[8*gix+7]);
        *(uint4*)&Pl[n * 72 + 8 * gix] = w;
    }

    // ---- PV via MFMA ----
    f32x4 o[4][2];
    #pragma unroll
    for (int i = 0; i < 4; ++i)
        #pragma unroll
        for (int j2 = 0; j2 < 2; ++j2)
            o[i][j2] = (f32x4)(0.0f);
    #pragma unroll
    for (int kh = 0; kh < 64; kh += 32) {
        bf16x8 pa[4], vb[2];
        #pragma unroll
        for (int i = 0; i < 4; ++i)
            pa[i] = *(const bf16x8*)&Pl[(16*i + m16) * 72 + kh + quad * 8];
        #pragma unroll
        for (int j2 = 0; j2 < 2; ++j2)
            vb[j2] = *(const bf16x8*)&Vt[(16*j2 + m16) * 72 + kh + quad * 8];
        #pragma unroll
        for (int i = 0; i < 4; ++i)
            #pragma unroll
            for (int j2 = 0; j2 < 2; ++j2)
                o[i][j2] = __builtin_amdgcn_mfma_f32_16x16x32_bf16(pa[i], vb[j2], o[i][j2], 0, 0, 0);
    }
    __syncthreads();   // all waves done with arenas -> AoT may overlay

    // ---- O -> shared AoT tile (bf16, token-major, stride 200) ----
    #pragma unroll
    for (int i = 0; i < 4; ++i) {
        #pragma unroll
        for (int r = 0; r < 4; ++r) {
            const int row = 16 * i + 4 * quad + r;
            AoT[row][h * 32 + m16]      = f2b(o[i][0][r]);
            AoT[row][h * 32 + 16 + m16] = f2b(o[i][1][r]);
        }
    }
    __syncthreads();

    // ---- proj: wave computes outs [wave*32, wave*32+32), K=192 ----
    f32x4 pacc[4][2];
    #pragma unroll
    for (int i = 0; i < 4; ++i)
        #pragma unroll
        for (int j = 0; j < 2; ++j)
            pacc[i][j] = (f32x4)(0.0f);
    const ushort_t* Wb = wpf + (size_t)(wave * 2) * 24 * 128 + m16 * 8;
    for (int ks = 0; ks < 192; ks += 32) {
        bf16x8 af[4], wv[2];
        #pragma unroll
        for (int i = 0; i < 4; ++i)
            af[i] = *(const bf16x8*)&AoT[16 * i + m16][quad * 8 + ks];
        #pragma unroll
        for (int j = 0; j < 2; ++j)
            wv[j] = *(const bf16x8*)(Wb + (size_t)(j * 24 + (ks >> 3) + quad) * 128);
        #pragma unroll
        for (int i = 0; i < 4; ++i)
            #pragma unroll
            for (int j = 0; j < 2; ++j)
                pacc[i][j] = __builtin_amdgcn_mfma_f32_16x16x32_bf16(wv[j], af[i], pacc[i][j], 0, 0, 0);
    }

    // ---- stage C^T (+bias) into per-wave Cww[64][36] ----
    float4 bj[2];
    #pragma unroll
    for (int j = 0; j < 2; ++j)
        bj[j] = *(const float4*)&proj_b[wave * 32 + 16 * j + quad * 4];
    #pragma unroll
    for (int i = 0; i < 4; ++i)
        #pragma unroll
        for (int j = 0; j < 2; ++j) {
            f32x4 v = pacc[i][j];
            v[0] += bj[j].x; v[1] += bj[j].y; v[2] += bj[j].z; v[3] += bj[j].w;
            *(f32x4*)&Cww[(16 * i + m16) * 36 + 16 * j + quad * 4] = v;
        }
    // wave-local Cww: no barrier needed

    // ---- store x2 = proj + shortcut(bf16) ----
    #pragma unroll
    for (int q = 0; q < 8; ++q) {
        const int idx = q * 64 + n;
        const int row = idx >> 3, c4 = (idx & 7) * 4;
        const int ii = row >> 3, jj = row & 7;
        const int tt = b * 4096 + (wh * 8 + ii) * 64 + ww * 8 + jj;
        float4 vv = *(const float4*)&Cww[row * 36 + c4];
        uint2 rv = *(const uint2*)&sc_h[(size_t)tt * 192 + wave * 32 + c4];
        vv.x += b2f((ushort_t)(rv.x & 0xffffu));
        vv.y += b2f((ushort_t)(rv.x >> 16));
        vv.z += b2f((ushort_t)(rv.y & 0xffffu));
        vv.w += b2f((ushort_t)(rv.y >> 16));
        *(float4*)&x2[(size_t)tt * DIM + wave * 32 + c4] = vv;
    }
}

// ---------------------------------------------------------------------------
// FUSED MLP kernel (r11-validated): LN2 -> fc1+GELU -> fc2 -> +res -> NCHW.
__global__ __launch_bounds__(256) void mlp_fused(
    const float* __restrict__ x2, const ushort_t* __restrict__ w1f,
    const ushort_t* __restrict__ w2f, const float* __restrict__ fc1_b,
    const float* __restrict__ fc2_b, const float* __restrict__ g2,
    const float* __restrict__ b2, float* __restrict__ outp)
{
    __shared__ __align__(16) char smem[43008];
    ushort_t (*h_h)[200] = (ushort_t(*)[200])smem;            // [64][200]
    ushort_t (*a1c)[136] = (ushort_t(*)[136])(smem + 25600);  // [64][136]
    float* gs  = (float*)(smem + 25600);                      // phase-1 only
    float* bs  = gs + 192;

    const int tid  = threadIdx.x;
    const int wave = tid >> 6, lane = tid & 63;
    const int m16 = lane & 15, quad = lane >> 4;
    const int t0 = blockIdx.x * 64;
    const int b   = t0 >> 12;
    const int hw0 = t0 & 4095;

    if (tid < 192) { gs[tid] = g2[tid]; bs[tid] = b2[tid]; }
    __syncthreads();
    {
        const int tok = tid >> 2, p = tid & 3;
        const float* rp = x2 + (size_t)(t0 + tok) * DIM + p * 48;
        float xv[48];
        #pragma unroll
        for (int c4 = 0; c4 < 12; ++c4)
            *(float4*)&xv[c4 * 4] = *(const float4*)(rp + c4 * 4);
        float sum = 0.f;
        #pragma unroll
        for (int c = 0; c < 48; ++c) sum += xv[c];
        sum += __shfl_xor(sum, 1);
        sum += __shfl_xor(sum, 2);
        const float m = sum * (1.0f / 192.0f);
        float ss = 0.f;
        #pragma unroll
        for (int c = 0; c < 48; ++c) { float d = xv[c] - m; ss += d * d; }
        ss += __shfl_xor(ss, 1);
        ss += __shfl_xor(ss, 2);
        const float rs = 1.0f / sqrtf(ss * (1.0f / 192.0f) + 1e-5f);
        ushort_t* hp = &h_h[tok][p * 48];
        #pragma unroll
        for (int c2 = 0; c2 < 24; ++c2) {
            float v0 = (xv[2*c2]   - m) * rs * gs[p * 48 + 2*c2]   + bs[p * 48 + 2*c2];
            float v1 = (xv[2*c2+1] - m) * rs * gs[p * 48 + 2*c2+1] + bs[p * 48 + 2*c2+1];
            *(unsigned*)(hp + 2 * c2) = pk2(v0, v1);
        }
    }
    __syncthreads();

    f32x4 acc2[4][3];
    #pragma unroll
    for (int i = 0; i < 4; ++i)
        #pragma unroll
        for (int j = 0; j < 3; ++j)
            acc2[i][j] = (f32x4)(0.0f);

    for (int c = 0; c < 6; ++c) {
        f32x4 acc1[4][2];
        #pragma unroll
        for (int i = 0; i < 4; ++i)
            #pragma unroll
            for (int j = 0; j < 2; ++j)
                acc1[i][j] = (f32x4)(0.0f);
        const ushort_t* Wb1 = w1f + (size_t)(c * 8 + wave * 2) * 24 * 128 + m16 * 8;
        for (int ks = 0; ks < 192; ks += 32) {
            bf16x8 af[4], wv[2];
            #pragma unroll
            for (int i = 0; i < 4; ++i)
                af[i] = *(const bf16x8*)&h_h[16 * i + m16][quad * 8 + ks];
            #pragma unroll
            for (int j = 0; j < 2; ++j)
                wv[j] = *(const bf16x8*)(Wb1 + (size_t)(j * 24 + (ks >> 3) + quad) * 128);
            #pragma unroll
            for (int i = 0; i < 4; ++i)
                #pragma unroll
                for (int j = 0; j < 2; ++j)
                    acc1[i][j] = __builtin_amdgcn_mfma_f32_16x16x32_bf16(wv[j], af[i], acc1[i][j], 0, 0, 0);
        }
        #pragma unroll
        for (int j = 0; j < 2; ++j) {
            const int o = c * 128 + wave * 32 + 16 * j + quad * 4;
            const float4 bv = *(const float4*)&fc1_b[o];
            #pragma unroll
            for (int i = 0; i < 4; ++i) {
                f32x4 v = acc1[i][j];
                v[0] += bv.x; v[1] += bv.y; v[2] += bv.z; v[3] += bv.w;
                #pragma unroll
                for (int r = 0; r < 4; ++r) {
                    float xg = v[r];
                    float e1 = __expf(xg * (1.5957691f + 0.0713548f * xg * xg)) + 1.0f;
                    v[r] = xg - xg * __builtin_amdgcn_rcpf(e1);
                }
                uint2 pkd;
                pkd.x = pk2(v[0], v[1]); pkd.y = pk2(v[2], v[3]);
                *(uint2*)&a1c[16 * i + m16][wave * 32 + 16 * j + quad * 4] = pkd;
            }
        }
        __syncthreads();
        const ushort_t* Wb2 = w2f + (size_t)(wave * 3) * 96 * 128 + m16 * 8;
        for (int ks = 0; ks < 128; ks += 32) {
            bf16x8 af2[4], wv2[3];
            #pragma unroll
            for (int i = 0; i < 4; ++i)
                af2[i] = *(const bf16x8*)&a1c[16 * i + m16][quad * 8 + ks];
            #pragma unroll
            for (int j = 0; j < 3; ++j)
                wv2[j] = *(const bf16x8*)(Wb2 + (size_t)(j * 96 + c * 16 + (ks >> 3) + quad) * 128);
            #pragma unroll
            for (int i = 0; i < 4; ++i)
                #pragma unroll
                for (int j = 0; j < 3; ++j)
                    acc2[i][j] = __builtin_amdgcn_mfma_f32_16x16x32_bf16(wv2[j], af2[i], acc2[i][j], 0, 0, 0);
        }
        __syncthreads();
    }

    float (*Cw)[68] = (float(*)[68])(smem + wave * 8704);
    float4 b2j[3];
    #pragma unroll
    for (int j = 0; j < 3; ++j)
        b2j[j] = *(const float4*)&fc2_b[wave * 48 + 16 * j + quad * 4];
    #pragma unroll
    for (int p = 0; p < 2; ++p) {
        #pragma unroll
        for (int ih = 0; ih < 2; ++ih) {
            const int i = 2 * p + ih;
            #pragma unroll
            for (int j = 0; j < 3; ++j) {
                f32x4 v = acc2[i][j];
                v[0] += b2j[j].x; v[1] += b2j[j].y; v[2] += b2j[j].z; v[3] += b2j[j].w;
                *(f32x4*)&Cw[ih * 16 + m16][16 * j + quad * 4] = v;
            }
        }
        #pragma unroll
        for (int q = 0; q < 6; ++q) {
            const int idx = q * 64 + lane;
            const int cc = idx >> 3, t4 = (idx & 7) * 4;
            const int o  = wave * 48 + cc;
            const int tb = t0 + p * 32 + t4;
            float4 vv;
            vv.x = Cw[t4 + 0][cc] + x2[(size_t)(tb + 0) * DIM + o];
            vv.y = Cw[t4 + 1][cc] + x2[(size_t)(tb + 1) * DIM + o];
            vv.z = Cw[t4 + 2][cc] + x2[(size_t)(tb + 2) * DIM + o];
            vv.w = Cw[t4 + 3][cc] + x2[(size_t)(tb + 3) * DIM + o];
            *(float4*)&outp[(size_t)b * (DIM * 4096) + (size_t)o * 4096
                            + hw0 + p * 32 + t4] = vv;
        }
    }
}

// ---------------------------------------------------------------------------
extern "C" void kernel_launch(void* const* d_in, const int* in_sizes, int n_in,
                              void* d_out, int out_size, void* d_ws, size_t ws_size,
                              hipStream_t stream)
{
    const float* x        = (const float*)d_in[0];
    const float* norm1_g  = (const float*)d_in[1];
    const float* norm1_b  = (const float*)d_in[2];
    const float* qkv_w    = (const float*)d_in[3];
    const float* qkv_b    = (const float*)d_in[4];
    const float* proj_w   = (const float*)d_in[5];
    const float* proj_b   = (const float*)d_in[6];
    const float* rpbt     = (const float*)d_in[7];
    const float* temp     = (const float*)d_in[8];
    const float* norm2_g  = (const float*)d_in[9];
    const float* norm2_b  = (const float*)d_in[10];
    const float* fc1_w    = (const float*)d_in[11];
    const float* fc1_b    = (const float*)d_in[12];
    const float* fc2_w    = (const float*)d_in[13];
    const float* fc2_b    = (const float*)d_in[14];
    float* out = (float*)d_out;

    // ws layout (bytes):
    //   [0,        12582912)  shortcut bf16 (LN1 out)
    //   [12582912, 37748736)  x2 f32
    //   [125829120,...)       weights bf16 (fragment order)
    char* wsb = (char*)d_ws;
    ushort_t* shortcut_h = (ushort_t*)wsb;
    float*    x2         = (float*)(wsb + 12582912);
    ushort_t* wq  = (ushort_t*)(wsb + 125829120);      // 576x192 = 110592
    ushort_t* wp  = wq + 110592;                       // 192x192 = 36864
    ushort_t* w1  = wp + 36864;                        // 768x192 = 147456
    ushort_t* w2  = w1 + 147456;                       // 192x768 = 147456

    // 0. merged weight conversions into fragment order, one launch
    hipLaunchKernelGGL(cvt_all_kernel, dim3(432), dim3(256), 0, stream,
                       qkv_w, proj_w, fc1_w, fc2_w, wq, wp, w1, w2);

    // 1. LN1 + transpose -> shortcut bf16
    hipLaunchKernelGGL(ln1_kernel, dim3(TTOT / 64), dim3(256), 0, stream,
                       x, norm1_g, norm1_b, shortcut_h);
    // 2. fused qkv + attention + proj + residual -> x2
    hipLaunchKernelGGL(attn_fused, dim3(NWIN), dim3(384), 0, stream,
                       shortcut_h, wq, qkv_b, rpbt, temp, wp, proj_b, x2);
    // 3. fused LN2 + fc1 + GELU + fc2 + residual + NCHW transpose
    hipLaunchKernelGGL(mlp_fused, dim3(TTOT / 64), dim3(256), 0, stream,
                       x2, w1, w2, fc1_b, fc2_b, norm2_g, norm2_b, out);
}